// Round 2
// baseline (4450.763 us; speedup 1.0000x reference)
//
#include <hip/hip_runtime.h>
#include <math.h>

#define B_   2
#define S_   2048
#define H_   2048
#define NH_  16
#define T_   (B_*S_)      // 4096 tokens
#define QL   1536
#define KVL  512
#define DN   128
#define DR   64
#define DQK  192          // DN + DR
#define DV   128
#define SCALE_ 0.07216878364870323f   // 1/sqrt(192)
#define EPS_ 1e-6f

// ---------------------------------------------------------------------------
// C = A @ W^T.  A: M x K (row-major, lda), W: N x K (row-major, ldw), C: M x N.
// 64x64 tile, 16x16 threads, 4x4 microtile. M,N multiples of 64; K multiple of 16.
// ---------------------------------------------------------------------------
__global__ __launch_bounds__(256) void gemm_xwt(
    const float* __restrict__ A, int lda,
    const float* __restrict__ W, int ldw,
    float* __restrict__ C, int ldc,
    int K) {
  __shared__ float As[16][68];  // [k][m], pad 68 -> rows 16B aligned
  __shared__ float Bs[16][68];  // [k][n]
  const int tx = threadIdx.x, ty = threadIdx.y;
  const int tid = ty * 16 + tx;
  const size_t m0 = blockIdx.y * 64;
  const size_t n0 = blockIdx.x * 64;

  float acc[4][4];
#pragma unroll
  for (int i = 0; i < 4; ++i)
#pragma unroll
    for (int j = 0; j < 4; ++j) acc[i][j] = 0.f;

  for (int k0 = 0; k0 < K; k0 += 16) {
#pragma unroll
    for (int i = 0; i < 4; ++i) {
      int idx = tid + i * 256;      // 0..1023
      int r = idx >> 4;             // 0..63
      int k = idx & 15;
      As[k][r] = A[(m0 + r) * (size_t)lda + k0 + k];
      Bs[k][r] = W[(n0 + r) * (size_t)ldw + k0 + k];
    }
    __syncthreads();
#pragma unroll
    for (int k = 0; k < 16; ++k) {
      float a[4], b[4];
#pragma unroll
      for (int i = 0; i < 4; ++i) a[i] = As[k][ty * 4 + i];
#pragma unroll
      for (int j = 0; j < 4; ++j) b[j] = Bs[k][tx * 4 + j];
#pragma unroll
      for (int i = 0; i < 4; ++i)
#pragma unroll
        for (int j = 0; j < 4; ++j) acc[i][j] += a[i] * b[j];
    }
    __syncthreads();
  }
#pragma unroll
  for (int i = 0; i < 4; ++i) {
    float4 v = make_float4(acc[i][0], acc[i][1], acc[i][2], acc[i][3]);
    *(float4*)&C[(m0 + ty * 4 + i) * (size_t)ldc + n0 + tx * 4] = v;
  }
}

// ---------------------------------------------------------------------------
// In-place RMSNorm over D elements of each row (row stride `stride`).
// ---------------------------------------------------------------------------
__global__ __launch_bounds__(256) void rmsnorm_kernel(
    float* __restrict__ x, const float* __restrict__ w, int D, int stride) {
  float* p = x + (size_t)blockIdx.x * stride;
  float ss = 0.f;
  for (int i = threadIdx.x; i < D; i += 256) { float v = p[i]; ss += v * v; }
#pragma unroll
  for (int off = 32; off; off >>= 1) ss += __shfl_down(ss, off);
  __shared__ float red[4];
  __shared__ float s_inv;
  if ((threadIdx.x & 63) == 0) red[threadIdx.x >> 6] = ss;
  __syncthreads();
  if (threadIdx.x == 0) {
    float t = red[0] + red[1] + red[2] + red[3];
    s_inv = 1.0f / sqrtf(t / (float)D + EPS_);
  }
  __syncthreads();
  float inv = s_inv;
  for (int i = threadIdx.x; i < D; i += 256) p[i] = w[i] * p[i] * inv;
}

// ---------------------------------------------------------------------------
// Interleaved RoPE, in place. One thread per (row, head, pair).
// ---------------------------------------------------------------------------
__global__ void rope_q_kernel(float* __restrict__ Q) {
  int idx = blockIdx.x * blockDim.x + threadIdx.x;   // T*NH*32
  int pair = idx & 31;
  int head = (idx >> 5) & (NH_ - 1);
  int row = idx >> 9;
  if (row >= T_) return;
  int s = row & (S_ - 1);
  float inv = powf(10000.0f, -(float)(2 * pair) * (1.0f / 64.0f));
  float ang = (float)s * inv;
  float c = cosf(ang), sn = sinf(ang);
  float* p = Q + (size_t)row * (NH_ * DQK) + head * DQK + DN + 2 * pair;
  float e = p[0], o = p[1];
  p[0] = e * c - o * sn;
  p[1] = e * sn + o * c;
}

__global__ void rope_k_kernel(float* __restrict__ KV) {
  int idx = blockIdx.x * blockDim.x + threadIdx.x;   // T*32
  int pair = idx & 31;
  int row = idx >> 5;
  if (row >= T_) return;
  int s = row & (S_ - 1);
  float inv = powf(10000.0f, -(float)(2 * pair) * (1.0f / 64.0f));
  float ang = (float)s * inv;
  float c = cosf(ang), sn = sinf(ang);
  float* p = KV + (size_t)row * (KVL + DR) + KVL + 2 * pair;
  float e = p[0], o = p[1];
  p[0] = e * c - o * sn;
  p[1] = e * sn + o * c;
}

// ---------------------------------------------------------------------------
// Flash attention (non-causal, full softmax over S keys).
// grid: (S/32, NH, B), block: 256.
// Qb:  T x 3072  (per head: [0..128)=q_nope, [128..192)=roped q_pe)
// KVx: T x 4096  (per head: [0..128)=k_nope, [128..256)=v)
// KVa: T x 576   ([512..576) = roped k_pe, shared across heads)
// Out: T x 2048  (per head 128)
// ---------------------------------------------------------------------------
__global__ __launch_bounds__(256) void flash_kernel(
    const float* __restrict__ Qb,
    const float* __restrict__ KVx,
    const float* __restrict__ KVa,
    float* __restrict__ Out) {
  const int h = blockIdx.y;
  const int b = blockIdx.z;
  const int q0 = blockIdx.x * 32;
  const int t0 = b * S_;

  __shared__ float Qs[32][196];   // pitch 196: rows 16B aligned
  __shared__ float Ks[32][196];   // reused as V tile (cols 0..127) after scores
  __shared__ float Ps[32][33];
  __shared__ float mrow[32], lrow[32], arow[32];

  const int tid = threadIdx.x;

  // Q tile: 32 rows x 48 float4
  for (int i = tid; i < 32 * 48; i += 256) {
    int r = i / 48, c = i % 48;
    *(float4*)&Qs[r][c * 4] =
        *(const float4*)(Qb + (size_t)(t0 + q0 + r) * (NH_ * DQK) + h * DQK + c * 4);
  }
  if (tid < 32) { mrow[tid] = -3e38f; lrow[tid] = 0.f; }

  float acc[16];
#pragma unroll
  for (int i = 0; i < 16; ++i) acc[i] = 0.f;
  const int q = tid & 31;
  const int g = tid >> 5;   // 0..7, owns d-columns [g*16, g*16+16)

  for (int k0 = 0; k0 < S_; k0 += 32) {
    __syncthreads();
    // K tile: k_nope (128) ++ k_pe (64)
    for (int i = tid; i < 32 * 48; i += 256) {
      int r = i / 48, c = i % 48;
      float4 v;
      if (c < 32)
        v = *(const float4*)(KVx + (size_t)(t0 + k0 + r) * 4096 + h * 256 + c * 4);
      else
        v = *(const float4*)(KVa + (size_t)(t0 + k0 + r) * (KVL + DR) + KVL + (c - 32) * 4);
      *(float4*)&Ks[r][c * 4] = v;
    }
    __syncthreads();
    // scores: thread (q, g) computes k = g*4 .. g*4+3
    {
      float s0 = 0, s1 = 0, s2 = 0, s3 = 0;
      for (int c = 0; c < 48; ++c) {
        float4 qv = *(const float4*)&Qs[q][c * 4];
        float4 k0v = *(const float4*)&Ks[g * 4 + 0][c * 4];
        float4 k1v = *(const float4*)&Ks[g * 4 + 1][c * 4];
        float4 k2v = *(const float4*)&Ks[g * 4 + 2][c * 4];
        float4 k3v = *(const float4*)&Ks[g * 4 + 3][c * 4];
        s0 += qv.x * k0v.x + qv.y * k0v.y + qv.z * k0v.z + qv.w * k0v.w;
        s1 += qv.x * k1v.x + qv.y * k1v.y + qv.z * k1v.z + qv.w * k1v.w;
        s2 += qv.x * k2v.x + qv.y * k2v.y + qv.z * k2v.z + qv.w * k2v.w;
        s3 += qv.x * k3v.x + qv.y * k3v.y + qv.z * k3v.z + qv.w * k3v.w;
      }
      Ps[q][g * 4 + 0] = s0 * SCALE_;
      Ps[q][g * 4 + 1] = s1 * SCALE_;
      Ps[q][g * 4 + 2] = s2 * SCALE_;
      Ps[q][g * 4 + 3] = s3 * SCALE_;
    }
    __syncthreads();
    // V tile into Ks cols [0..128); softmax row pass runs concurrently on tid<32
    for (int i = tid; i < 32 * 32; i += 256) {
      int r = i >> 5, c = i & 31;
      *(float4*)&Ks[r][c * 4] =
          *(const float4*)(KVx + (size_t)(t0 + k0 + r) * 4096 + h * 256 + 128 + c * 4);
    }
    if (tid < 32) {
      float mo = mrow[tid];
      float mt = mo;
#pragma unroll
      for (int k = 0; k < 32; ++k) mt = fmaxf(mt, Ps[tid][k]);
      float alpha = __expf(mo - mt);
      float sum = 0.f;
#pragma unroll
      for (int k = 0; k < 32; ++k) {
        float p = __expf(Ps[tid][k] - mt);
        Ps[tid][k] = p;
        sum += p;
      }
      mrow[tid] = mt;
      lrow[tid] = lrow[tid] * alpha + sum;
      arow[tid] = alpha;
    }
    __syncthreads();
    // O update
    {
      float alpha = arow[q];
#pragma unroll
      for (int i = 0; i < 16; ++i) acc[i] *= alpha;
#pragma unroll 4
      for (int k = 0; k < 32; ++k) {
        float p = Ps[q][k];
        const float* vp = &Ks[k][g * 16];
        float4 v0 = *(const float4*)(vp);
        float4 v1 = *(const float4*)(vp + 4);
        float4 v2 = *(const float4*)(vp + 8);
        float4 v3 = *(const float4*)(vp + 12);
        acc[0] += p * v0.x;  acc[1] += p * v0.y;  acc[2] += p * v0.z;  acc[3] += p * v0.w;
        acc[4] += p * v1.x;  acc[5] += p * v1.y;  acc[6] += p * v1.z;  acc[7] += p * v1.w;
        acc[8] += p * v2.x;  acc[9] += p * v2.y;  acc[10] += p * v2.z; acc[11] += p * v2.w;
        acc[12] += p * v3.x; acc[13] += p * v3.y; acc[14] += p * v3.z; acc[15] += p * v3.w;
      }
    }
  }
  float invl = 1.0f / lrow[q];
  float* op = Out + (size_t)(t0 + q0 + q) * (NH_ * DV) + h * DV + g * 16;
#pragma unroll
  for (int i = 0; i < 4; ++i) {
    float4 v = make_float4(acc[i * 4] * invl, acc[i * 4 + 1] * invl,
                           acc[i * 4 + 2] * invl, acc[i * 4 + 3] * invl);
    *(float4*)(op + i * 4) = v;
  }
}

// ---------------------------------------------------------------------------
// Workspace layout (floats), with q_a aliased onto the attn region:
//   [attn | q_a]   : T * 2048   (q_a needs T*1536, dead before flash writes attn)
//   q_b            : T * 3072
//   kv_a           : T * 576
//   kv_x           : T * 4096
// peak = T * (2048+3072+576+4096) = 40,108,032 floats = 160.4 MB
// ---------------------------------------------------------------------------
extern "C" void kernel_launch(void* const* d_in, const int* in_sizes, int n_in,
                              void* d_out, int out_size, void* d_ws, size_t ws_size,
                              hipStream_t stream) {
  const float* hidden  = (const float*)d_in[0];
  const float* wq_a    = (const float*)d_in[1];
  const float* q_norm  = (const float*)d_in[2];
  const float* wq_b    = (const float*)d_in[3];
  const float* wkv_a   = (const float*)d_in[4];
  const float* kv_norm = (const float*)d_in[5];
  const float* wkv_b   = (const float*)d_in[6];
  const float* wo      = (const float*)d_in[7];
  float* out = (float*)d_out;

  const size_t need = (size_t)T_ * (2048 + 3072 + 576 + 4096) * sizeof(float);
  if (ws_size < need) return;  // clean failure instead of OOB scribble

  float* ws   = (float*)d_ws;
  float* attn = ws;                                   // T x 2048
  float* q_a  = ws;                                   // T x 1536 (aliases attn; dead before flash)
  float* q_b  = attn + (size_t)T_ * 2048;             // T x 3072
  float* kv_a = q_b  + (size_t)T_ * NH_ * DQK;        // T x 576
  float* kv_x = kv_a + (size_t)T_ * (KVL + DR);       // T x 4096

  dim3 blk(16, 16);

  // q = rmsnorm(hidden @ wq_a.T) @ wq_b.T
  gemm_xwt<<<dim3(QL / 64, T_ / 64), blk, 0, stream>>>(hidden, H_, wq_a, H_, q_a, QL, H_);
  rmsnorm_kernel<<<T_, 256, 0, stream>>>(q_a, q_norm, QL, QL);
  gemm_xwt<<<dim3(NH_ * DQK / 64, T_ / 64), blk, 0, stream>>>(q_a, QL, wq_b, QL, q_b, NH_ * DQK, QL);

  // kv = hidden @ wkv_a.T ; rmsnorm(kv_c) ; rope(k_pe)
  gemm_xwt<<<dim3((KVL + DR) / 64, T_ / 64), blk, 0, stream>>>(hidden, H_, wkv_a, H_, kv_a, KVL + DR, H_);
  rmsnorm_kernel<<<T_, 256, 0, stream>>>(kv_a, kv_norm, KVL, KVL + DR);
  rope_k_kernel<<<T_ * 32 / 256, 256, 0, stream>>>(kv_a);

  // kv_x = kv_c @ wkv_b.T
  gemm_xwt<<<dim3(NH_ * (DN + DV) / 64, T_ / 64), blk, 0, stream>>>(kv_a, KVL + DR, wkv_b, KVL, kv_x, NH_ * (DN + DV), KVL);

  // rope(q_pe)
  rope_q_kernel<<<T_ * NH_ * 32 / 256, 256, 0, stream>>>(q_b);

  // attention
  flash_kernel<<<dim3(S_ / 32, NH_, B_), 256, 0, stream>>>(q_b, kv_x, kv_a, attn);

  // out = attn @ wo.T
  gemm_xwt<<<dim3(H_ / 64, T_ / 64), blk, 0, stream>>>(attn, NH_ * DV, wo, NH_ * DV, out, H_, NH_ * DV);
}

// Round 3
// 2231.672 us; speedup vs baseline: 1.9944x; 1.9944x over previous
//
#include <hip/hip_runtime.h>
#include <math.h>

#define B_   2
#define S_   2048
#define H_   2048
#define NH_  16
#define T_   (B_*S_)      // 4096 tokens
#define QL   1536
#define KVL  512
#define DN   128
#define DR   64
#define DQK  192          // DN + DR
#define DV   128
#define SCALE_ 0.07216878364870323f   // 1/sqrt(192)
#define EPS_ 1e-6f

typedef unsigned short u16;
typedef __attribute__((ext_vector_type(8))) short bf16x8;  // 8 bf16 = 4 VGPRs
typedef __attribute__((ext_vector_type(4))) float f32x4;   // MFMA C/D frag

__device__ __forceinline__ u16 f2b(float x) {   // fp32 -> bf16 RNE
  union { float f; unsigned u; } v; v.f = x;
  unsigned r = v.u + 0x7FFFu + ((v.u >> 16) & 1u);
  return (u16)(r >> 16);
}
__device__ __forceinline__ float b2f(u16 u) {
  union { unsigned u; float f; } v; v.u = ((unsigned)u) << 16; return v.f;
}

// ---------------------------------------------------------------------------
// fp32 GEMM: C = A @ W^T (as round 2).
// ---------------------------------------------------------------------------
__global__ __launch_bounds__(256) void gemm_xwt(
    const float* __restrict__ A, int lda,
    const float* __restrict__ W, int ldw,
    float* __restrict__ C, int ldc,
    int K) {
  __shared__ float As[16][68];
  __shared__ float Bs[16][68];
  const int tx = threadIdx.x, ty = threadIdx.y;
  const int tid = ty * 16 + tx;
  const size_t m0 = blockIdx.y * 64;
  const size_t n0 = blockIdx.x * 64;
  float acc[4][4];
#pragma unroll
  for (int i = 0; i < 4; ++i)
#pragma unroll
    for (int j = 0; j < 4; ++j) acc[i][j] = 0.f;
  for (int k0 = 0; k0 < K; k0 += 16) {
#pragma unroll
    for (int i = 0; i < 4; ++i) {
      int idx = tid + i * 256;
      int r = idx >> 4, k = idx & 15;
      As[k][r] = A[(m0 + r) * (size_t)lda + k0 + k];
      Bs[k][r] = W[(n0 + r) * (size_t)ldw + k0 + k];
    }
    __syncthreads();
#pragma unroll
    for (int k = 0; k < 16; ++k) {
      float a[4], b[4];
#pragma unroll
      for (int i = 0; i < 4; ++i) a[i] = As[k][ty * 4 + i];
#pragma unroll
      for (int j = 0; j < 4; ++j) b[j] = Bs[k][tx * 4 + j];
#pragma unroll
      for (int i = 0; i < 4; ++i)
#pragma unroll
        for (int j = 0; j < 4; ++j) acc[i][j] += a[i] * b[j];
    }
    __syncthreads();
  }
#pragma unroll
  for (int i = 0; i < 4; ++i) {
    float4 v = make_float4(acc[i][0], acc[i][1], acc[i][2], acc[i][3]);
    *(float4*)&C[(m0 + ty * 4 + i) * (size_t)ldc + n0 + tx * 4] = v;
  }
}

// Same GEMM, bf16 output with epilogue scale.
__global__ __launch_bounds__(256) void gemm_xwt_bf16(
    const float* __restrict__ A, int lda,
    const float* __restrict__ W, int ldw,
    u16* __restrict__ C, int ldc,
    int K, float outscale) {
  __shared__ float As[16][68];
  __shared__ float Bs[16][68];
  const int tx = threadIdx.x, ty = threadIdx.y;
  const int tid = ty * 16 + tx;
  const size_t m0 = blockIdx.y * 64;
  const size_t n0 = blockIdx.x * 64;
  float acc[4][4];
#pragma unroll
  for (int i = 0; i < 4; ++i)
#pragma unroll
    for (int j = 0; j < 4; ++j) acc[i][j] = 0.f;
  for (int k0 = 0; k0 < K; k0 += 16) {
#pragma unroll
    for (int i = 0; i < 4; ++i) {
      int idx = tid + i * 256;
      int r = idx >> 4, k = idx & 15;
      As[k][r] = A[(m0 + r) * (size_t)lda + k0 + k];
      Bs[k][r] = W[(n0 + r) * (size_t)ldw + k0 + k];
    }
    __syncthreads();
#pragma unroll
    for (int k = 0; k < 16; ++k) {
      float a[4], b[4];
#pragma unroll
      for (int i = 0; i < 4; ++i) a[i] = As[k][ty * 4 + i];
#pragma unroll
      for (int j = 0; j < 4; ++j) b[j] = Bs[k][tx * 4 + j];
#pragma unroll
      for (int i = 0; i < 4; ++i)
#pragma unroll
        for (int j = 0; j < 4; ++j) acc[i][j] += a[i] * b[j];
    }
    __syncthreads();
  }
#pragma unroll
  for (int i = 0; i < 4; ++i) {
    unsigned lo = (unsigned)f2b(acc[i][0] * outscale) | ((unsigned)f2b(acc[i][1] * outscale) << 16);
    unsigned hi = (unsigned)f2b(acc[i][2] * outscale) | ((unsigned)f2b(acc[i][3] * outscale) << 16);
    uint2 v = make_uint2(lo, hi);
    *(uint2*)&C[(m0 + ty * 4 + i) * (size_t)ldc + n0 + tx * 4] = v;
  }
}

// ---------------------------------------------------------------------------
__global__ __launch_bounds__(256) void rmsnorm_kernel(
    float* __restrict__ x, const float* __restrict__ w, int D, int stride) {
  float* p = x + (size_t)blockIdx.x * stride;
  float ss = 0.f;
  for (int i = threadIdx.x; i < D; i += 256) { float v = p[i]; ss += v * v; }
#pragma unroll
  for (int off = 32; off; off >>= 1) ss += __shfl_down(ss, off);
  __shared__ float red[4];
  __shared__ float s_inv;
  if ((threadIdx.x & 63) == 0) red[threadIdx.x >> 6] = ss;
  __syncthreads();
  if (threadIdx.x == 0) {
    float t = red[0] + red[1] + red[2] + red[3];
    s_inv = 1.0f / sqrtf(t / (float)D + EPS_);
  }
  __syncthreads();
  float inv = s_inv;
  for (int i = threadIdx.x; i < D; i += 256) p[i] = w[i] * p[i] * inv;
}

// ---------------------------------------------------------------------------
// RoPE in place on bf16 q_pe. Q_bf: [T][NH*192], pe at +128 per head.
// ---------------------------------------------------------------------------
__global__ void rope_q_bf(u16* __restrict__ Q) {
  int idx = blockIdx.x * blockDim.x + threadIdx.x;   // T*NH*32
  int pair = idx & 31;
  int head = (idx >> 5) & (NH_ - 1);
  int row = idx >> 9;
  if (row >= T_) return;
  int s = row & (S_ - 1);
  float inv = powf(10000.0f, -(float)(2 * pair) * (1.0f / 64.0f));
  float ang = (float)s * inv;
  float c = cosf(ang), sn = sinf(ang);
  u16* p = Q + (size_t)row * (NH_ * DQK) + head * DQK + DN + 2 * pair;
  unsigned u = *(unsigned*)p;
  float e = b2f((u16)(u & 0xffff)), o = b2f((u16)(u >> 16));
  float re = e * c - o * sn;
  float im = e * sn + o * c;
  *(unsigned*)p = (unsigned)f2b(re) | ((unsigned)f2b(im) << 16);
}

// k_pe: read raw fp32 from kv_a cols [512,576), rope, -> bf16 KPE [T][64].
__global__ void kpe_bf_kernel(const float* __restrict__ KVa, u16* __restrict__ KPE) {
  int idx = blockIdx.x * blockDim.x + threadIdx.x;   // T*32
  int pair = idx & 31;
  int row = idx >> 5;
  if (row >= T_) return;
  int s = row & (S_ - 1);
  float inv = powf(10000.0f, -(float)(2 * pair) * (1.0f / 64.0f));
  float ang = (float)s * inv;
  float c = cosf(ang), sn = sinf(ang);
  const float* p = KVa + (size_t)row * (KVL + DR) + KVL + 2 * pair;
  float e = p[0], o = p[1];
  float re = e * c - o * sn;
  float im = e * sn + o * c;
  *(unsigned*)(KPE + (size_t)row * 64 + 2 * pair) =
      (unsigned)f2b(re) | ((unsigned)f2b(im) << 16);
}

// ---------------------------------------------------------------------------
// V transpose: KVbf [T][NH*256] (v at +128 per head, bf16) -> Vt [B*NH*128][2048].
// grid (64, NH, B): bx -> s0=(bx>>1)*64, d0=(bx&1)*64. block 256.
// ---------------------------------------------------------------------------
__global__ __launch_bounds__(256) void conv_vt(const u16* __restrict__ KVbf,
                                               u16* __restrict__ Vt) {
  const int h = blockIdx.y, b = blockIdx.z;
  const int s0 = (blockIdx.x >> 1) * 64, d0 = (blockIdx.x & 1) * 64;
  const int t0 = b * S_;
  __shared__ u16 tile[64][72];   // [s][d], pitch 144 B (16B-aligned rows)
  const int tid = threadIdx.x;
#pragma unroll
  for (int i = 0; i < 2; ++i) {
    int c = tid + i * 256;        // 0..511 : 64 rows x 8 chunks
    int row = c >> 3, off = (c & 7) * 8;
    *(uint4*)&tile[row][off] =
        *(const uint4*)(KVbf + (size_t)(t0 + s0 + row) * 4096 + h * 256 + 128 + d0 + off);
  }
  __syncthreads();
#pragma unroll
  for (int i = 0; i < 2; ++i) {
    int c = tid + i * 256;
    int drow = c >> 3, soff = (c & 7) * 8;
    u16 vals[8];
#pragma unroll
    for (int j = 0; j < 8; ++j) vals[j] = tile[soff + j][drow];
    *(uint4*)(Vt + ((size_t)(b * NH_ + h) * 128 + d0 + drow) * 2048 + s0 + soff) =
        *(uint4*)vals;
  }
}

// ---------------------------------------------------------------------------
// MFMA flash attention. grid (S/64, NH, B), block 256 (4 waves x 16 q-rows).
// Qbf: [T][NH*192] bf16, pre-scaled by 1/sqrt(192), roped.
// KVbf: [T][NH*256] bf16 (k_nope at +0, v at +128 per head).
// KPE:  [T][64] bf16 roped.   Vt: [B*NH*128][2048] bf16.
// Out (attn): [T][2048] fp32.
// MFMA layouts (HW-verified): A: m=lane&15, k=quad*8+j. B: n=lane&15, k=quad*8+j.
// C/D: col(n)=lane&15, row(m)=quad*4+reg.
// ---------------------------------------------------------------------------
__global__ __launch_bounds__(256) void flash_mfma(
    const u16* __restrict__ Qbf,
    const u16* __restrict__ KVbf,
    const u16* __restrict__ KPE,
    const u16* __restrict__ Vt,
    float* __restrict__ Out) {
  const int h = blockIdx.y, b = blockIdx.z;
  const int q0 = blockIdx.x * 64;
  const int t0 = b * S_;
  const int tid = threadIdx.x;
  const int wave = tid >> 6, lane = tid & 63, quad = lane >> 4, l16 = lane & 15;

  __shared__ u16 Ks[64][200];      // [key][d 0..191], pitch 400 B
  __shared__ u16 Vs[128][72];      // [d][key 0..63], pitch 144 B
  __shared__ u16 Ps[4][16][72];    // per-wave P [q 0..15][key 0..63]

  // Q fragments (held in registers across the whole K loop)
  bf16x8 qf[6];
  {
    const u16* qp = Qbf + (size_t)(t0 + q0 + wave * 16 + l16) * (NH_ * DQK) + h * DQK + quad * 8;
#pragma unroll
    for (int c = 0; c < 6; ++c) qf[c] = *(const bf16x8*)(qp + c * 32);
  }

  f32x4 of[8];
#pragma unroll
  for (int i = 0; i < 8; ++i) of[i] = (f32x4){0.f, 0.f, 0.f, 0.f};
  float mrun[4] = {-3e38f, -3e38f, -3e38f, -3e38f};
  float lrun[4] = {0.f, 0.f, 0.f, 0.f};

  for (int kt = 0; kt < S_; kt += 64) {
    __syncthreads();
    // stage K tile: 64 keys x (128 nope + 64 pe) bf16
#pragma unroll
    for (int i = 0; i < 6; ++i) {
      int c = tid + i * 256;            // 0..1535 = 64 rows x 24 chunks
      int row = c / 24, off = c % 24;
      const u16* src = (off < 16)
          ? KVbf + (size_t)(t0 + kt + row) * 4096 + h * 256 + off * 8
          : KPE + (size_t)(t0 + kt + row) * 64 + (off - 16) * 8;
      *(uint4*)&Ks[row][off * 8] = *(const uint4*)src;
    }
    // stage V^T tile: 128 d x 64 keys
#pragma unroll
    for (int i = 0; i < 4; ++i) {
      int c = tid + i * 256;            // 0..1023 = 128 rows x 8 chunks
      int row = c >> 3, off = (c & 7) * 8;
      *(uint4*)&Vs[row][off] =
          *(const uint4*)(Vt + ((size_t)(b * NH_ + h) * 128 + row) * 2048 + kt + off);
    }
    __syncthreads();

    // ---- scores: 4 key-subtiles of 16, K-dim 192 = 6 mfma each ----
    f32x4 sc[4];
#pragma unroll
    for (int kk = 0; kk < 4; ++kk) {
      f32x4 s = (f32x4){0.f, 0.f, 0.f, 0.f};
#pragma unroll
      for (int c = 0; c < 6; ++c) {
        bf16x8 kf = *(const bf16x8*)&Ks[kk * 16 + l16][quad * 8 + c * 32];
        s = __builtin_amdgcn_mfma_f32_16x16x32_bf16(qf[c], kf, s, 0, 0, 0);
      }
      sc[kk] = s;
    }
    // ---- online softmax (rows = quad*4+r, cols spread over 16 lanes) ----
    float tm[4];
#pragma unroll
    for (int r = 0; r < 4; ++r)
      tm[r] = fmaxf(fmaxf(sc[0][r], sc[1][r]), fmaxf(sc[2][r], sc[3][r]));
#pragma unroll
    for (int off = 1; off < 16; off <<= 1)
#pragma unroll
      for (int r = 0; r < 4; ++r) tm[r] = fmaxf(tm[r], __shfl_xor(tm[r], off, 64));
    float alpha[4], rs[4], p[4][4];
#pragma unroll
    for (int r = 0; r < 4; ++r) {
      float mnew = fmaxf(mrun[r], tm[r]);
      alpha[r] = __expf(mrun[r] - mnew);
      mrun[r] = mnew;
      float s0 = 0.f;
#pragma unroll
      for (int kk = 0; kk < 4; ++kk) {
        float pv = __expf(sc[kk][r] - mnew);
        p[kk][r] = pv;
        s0 += pv;
      }
      rs[r] = s0;
    }
#pragma unroll
    for (int off = 1; off < 16; off <<= 1)
#pragma unroll
      for (int r = 0; r < 4; ++r) rs[r] += __shfl_xor(rs[r], off, 64);
#pragma unroll
    for (int r = 0; r < 4; ++r) lrun[r] = lrun[r] * alpha[r] + rs[r];

    // ---- P: C-layout -> LDS -> A-layout (wave-private region) ----
#pragma unroll
    for (int kk = 0; kk < 4; ++kk)
#pragma unroll
      for (int r = 0; r < 4; ++r)
        Ps[wave][quad * 4 + r][kk * 16 + l16] = f2b(p[kk][r]);

    // rescale O by alpha (C-layout rows match reg index)
#pragma unroll
    for (int dt = 0; dt < 8; ++dt)
#pragma unroll
      for (int r = 0; r < 4; ++r) of[dt][r] *= alpha[r];

    bf16x8 pa0 = *(const bf16x8*)&Ps[wave][l16][quad * 8];
    bf16x8 pa1 = *(const bf16x8*)&Ps[wave][l16][32 + quad * 8];
#pragma unroll
    for (int dt = 0; dt < 8; ++dt) {
      bf16x8 v0 = *(const bf16x8*)&Vs[dt * 16 + l16][quad * 8];
      bf16x8 v1 = *(const bf16x8*)&Vs[dt * 16 + l16][32 + quad * 8];
      of[dt] = __builtin_amdgcn_mfma_f32_16x16x32_bf16(pa0, v0, of[dt], 0, 0, 0);
      of[dt] = __builtin_amdgcn_mfma_f32_16x16x32_bf16(pa1, v1, of[dt], 0, 0, 0);
    }
  }

  // epilogue: divide by l, write fp32 attn
#pragma unroll
  for (int r = 0; r < 4; ++r) {
    float inv = 1.0f / lrun[r];
    float* op = Out + (size_t)(t0 + q0 + wave * 16 + quad * 4 + r) * (NH_ * DV) + h * DV + l16;
#pragma unroll
    for (int dt = 0; dt < 8; ++dt) op[dt * 16] = of[dt][r] * inv;
  }
}

// ---------------------------------------------------------------------------
// Workspace (floats): no aliasing. total = 36,044,800 fl = 144.2 MB
// ---------------------------------------------------------------------------
extern "C" void kernel_launch(void* const* d_in, const int* in_sizes, int n_in,
                              void* d_out, int out_size, void* d_ws, size_t ws_size,
                              hipStream_t stream) {
  const float* hidden  = (const float*)d_in[0];
  const float* wq_a    = (const float*)d_in[1];
  const float* q_norm  = (const float*)d_in[2];
  const float* wq_b    = (const float*)d_in[3];
  const float* wkv_a   = (const float*)d_in[4];
  const float* kv_norm = (const float*)d_in[5];
  const float* wkv_b   = (const float*)d_in[6];
  const float* wo      = (const float*)d_in[7];
  float* out = (float*)d_out;

  float* ws = (float*)d_ws;
  float*  q_a   = ws;                                   // T*1536 fl   (6,291,456)
  u16*    q_bf  = (u16*)(ws + 6291456);                 // T*3072 u16  (6,291,456 fl)
  float*  kv_a  = ws + 6291456 + 6291456;               // T*576 fl    (2,359,296)
  u16*    kv_bf = (u16*)(ws + 14942208);                // T*4096 u16  (8,388,608 fl)
  u16*    kpe   = (u16*)(ws + 23330816);                // T*64 u16    (131,072 fl)
  u16*    vt    = (u16*)(ws + 23461888);                // T*2048 u16  (4,194,304 fl)
  float*  attn  = ws + 27656192;                        // T*2048 fl   (8,388,608)
  const size_t need = (size_t)(27656192 + 8388608) * sizeof(float);
  if (ws_size < need) return;

  dim3 blk(16, 16);

  // q path
  gemm_xwt<<<dim3(QL / 64, T_ / 64), blk, 0, stream>>>(hidden, H_, wq_a, H_, q_a, QL, H_);
  rmsnorm_kernel<<<T_, 256, 0, stream>>>(q_a, q_norm, QL, QL);
  gemm_xwt_bf16<<<dim3(NH_ * DQK / 64, T_ / 64), blk, 0, stream>>>(
      q_a, QL, wq_b, QL, q_bf, NH_ * DQK, QL, SCALE_);
  rope_q_bf<<<T_ * NH_ * 32 / 256, 256, 0, stream>>>(q_bf);

  // kv path
  gemm_xwt<<<dim3((KVL + DR) / 64, T_ / 64), blk, 0, stream>>>(hidden, H_, wkv_a, H_, kv_a, KVL + DR, H_);
  rmsnorm_kernel<<<T_, 256, 0, stream>>>(kv_a, kv_norm, KVL, KVL + DR);
  kpe_bf_kernel<<<T_ * 32 / 256, 256, 0, stream>>>(kv_a, kpe);
  gemm_xwt_bf16<<<dim3(NH_ * (DN + DV) / 64, T_ / 64), blk, 0, stream>>>(
      kv_a, KVL + DR, wkv_b, KVL, kv_bf, NH_ * (DN + DV), KVL, 1.0f);
  conv_vt<<<dim3(64, NH_, B_), 256, 0, stream>>>(kv_bf, vt);

  // attention
  flash_mfma<<<dim3(S_ / 64, NH_, B_), 256, 0, stream>>>(q_bf, kv_bf, kpe, vt, attn);

  // out = attn @ wo.T
  gemm_xwt<<<dim3(H_ / 64, T_ / 64), blk, 0, stream>>>(attn, NH_ * DV, wo, NH_ * DV, out, H_, NH_ * DV);
}

// Round 4
// 710.164 us; speedup vs baseline: 6.2672x; 3.1425x over previous
//
#include <hip/hip_runtime.h>
#include <math.h>

#define B_   2
#define S_   2048
#define H_   2048
#define NH_  16
#define T_   (B_*S_)      // 4096 tokens
#define QL   1536
#define KVL  512
#define DN   128
#define DR   64
#define DQK  192          // DN + DR
#define DV   128
#define SCALE_ 0.07216878364870323f   // 1/sqrt(192)
#define EPS_ 1e-6f

typedef unsigned short u16;
typedef __attribute__((ext_vector_type(8))) short bf16x8;  // 8 bf16 = 4 VGPRs
typedef __attribute__((ext_vector_type(4))) float f32x4;   // MFMA C/D frag

__device__ __forceinline__ u16 f2b(float x) {   // fp32 -> bf16 RNE
  union { float f; unsigned u; } v; v.f = x;
  unsigned r = v.u + 0x7FFFu + ((v.u >> 16) & 1u);
  return (u16)(r >> 16);
}
__device__ __forceinline__ float b2f(u16 u) {
  union { unsigned u; float f; } v; v.u = ((unsigned)u) << 16; return v.f;
}

#define GLD16(src, dst) __builtin_amdgcn_global_load_lds(                       \
    (const __attribute__((address_space(1))) unsigned int*)(src),               \
    (__attribute__((address_space(3))) unsigned int*)(dst), 16, 0, 0)

// ---------------------------------------------------------------------------
// fp32 -> bf16 elementwise (n multiple of 4).
// ---------------------------------------------------------------------------
__global__ __launch_bounds__(256) void cvt_bf16(const float* __restrict__ in,
                                                u16* __restrict__ out, int n4) {
  int i = blockIdx.x * 256 + threadIdx.x;
  if (i >= n4) return;
  float4 v = ((const float4*)in)[i];
  u16 r[4] = {f2b(v.x), f2b(v.y), f2b(v.z), f2b(v.w)};
  ((uint2*)out)[i] = *(uint2*)r;
}

// wkv_a (576 x 2048) -> bf16 640 x 2048, rows [576,640) zeroed.
__global__ __launch_bounds__(256) void cvt_wkva(const float* __restrict__ in,
                                                u16* __restrict__ out) {
  int i = blockIdx.x * 256 + threadIdx.x;     // 640*512 float4 chunks
  if (i >= 640 * 512) return;
  int row = i >> 9;
  u16 r[4] = {0, 0, 0, 0};
  if (row < 576) {
    float4 v = ((const float4*)in)[i];
    r[0] = f2b(v.x); r[1] = f2b(v.y); r[2] = f2b(v.z); r[3] = f2b(v.w);
  }
  ((uint2*)out)[i] = *(uint2*)r;
}

// ---------------------------------------------------------------------------
// bf16 MFMA GEMM: C = A @ W^T.  A: M x K bf16 (lda), W: N x K bf16 (ldw).
// 128x128 tile, 4 waves (2x2 of 64x64), BK=32, 16x16x32 MFMA.
// LDS granule layout [tile16][kc][row16]x16B: DMA staging is lane-contiguous,
// fragment ds_read_b128 reads 64 consecutive granules per wave (conflict-free).
// OUTMODE: 0 = fp32 out, 1 = bf16 out (scaled).
// M,N multiples of 128; K multiple of 32.
// ---------------------------------------------------------------------------
template <int OUTMODE>
__global__ __launch_bounds__(256) void gemm_mfma(
    const u16* __restrict__ A, int lda,
    const u16* __restrict__ W, int ldw,
    float* __restrict__ Cf, u16* __restrict__ Cb, int ldc,
    int K, float outscale) {
  __shared__ u16 As[4096];   // 8 KB
  __shared__ u16 Bs[4096];
  const int tid = threadIdx.x;
  const int wave = tid >> 6, lane = tid & 63, quad = lane >> 4, l16 = lane & 15;
  const int wm = (wave >> 1) * 64, wn = (wave & 1) * 64;
  const size_t m0 = (size_t)blockIdx.y * 128, n0 = (size_t)blockIdx.x * 128;

  f32x4 acc[4][4];
#pragma unroll
  for (int i = 0; i < 4; ++i)
#pragma unroll
    for (int j = 0; j < 4; ++j) acc[i][j] = (f32x4){0.f, 0.f, 0.f, 0.f};

  // staging source pointers: granule g -> tile g>>6, kc (g>>4)&3, row16 g&15
  const int g0 = tid, g1 = tid + 256;
  const u16* a0 = A + (m0 + (g0 >> 6) * 16 + (g0 & 15)) * (size_t)lda + ((g0 >> 4) & 3) * 8;
  const u16* a1 = A + (m0 + (g1 >> 6) * 16 + (g1 & 15)) * (size_t)lda + ((g1 >> 4) & 3) * 8;
  const u16* b0 = W + (n0 + (g0 >> 6) * 16 + (g0 & 15)) * (size_t)ldw + ((g0 >> 4) & 3) * 8;
  const u16* b1 = W + (n0 + (g1 >> 6) * 16 + (g1 & 15)) * (size_t)ldw + ((g1 >> 4) & 3) * 8;

  for (int k0 = 0; k0 < K; k0 += 32) {
    __syncthreads();
    GLD16(a0 + k0, &As[g0 * 8]);
    GLD16(a1 + k0, &As[g1 * 8]);
    GLD16(b0 + k0, &Bs[g0 * 8]);
    GLD16(b1 + k0, &Bs[g1 * 8]);
    __syncthreads();

    bf16x8 af[4], bfr[4];
#pragma unroll
    for (int i = 0; i < 4; ++i)
      af[i] = *(const bf16x8*)&As[((wm >> 4) + i) * 512 + quad * 128 + l16 * 8];
#pragma unroll
    for (int j = 0; j < 4; ++j)
      bfr[j] = *(const bf16x8*)&Bs[((wn >> 4) + j) * 512 + quad * 128 + l16 * 8];
#pragma unroll
    for (int i = 0; i < 4; ++i)
#pragma unroll
      for (int j = 0; j < 4; ++j)
        acc[i][j] = __builtin_amdgcn_mfma_f32_16x16x32_bf16(af[i], bfr[j], acc[i][j], 0, 0, 0);
  }

#pragma unroll
  for (int i = 0; i < 4; ++i)
#pragma unroll
    for (int j = 0; j < 4; ++j)
#pragma unroll
      for (int r = 0; r < 4; ++r) {
        size_t m = m0 + wm + i * 16 + quad * 4 + r;
        size_t n = n0 + wn + j * 16 + l16;
        if (OUTMODE == 0) Cf[m * ldc + n] = acc[i][j][r];
        else              Cb[m * ldc + n] = f2b(acc[i][j][r] * outscale);
      }
}

// ---------------------------------------------------------------------------
// RMSNorm: fp32 in (row stride sx), bf16 out (row stride so), D cols.
// ---------------------------------------------------------------------------
__global__ __launch_bounds__(256) void rmsnorm_bf(
    const float* __restrict__ x, const float* __restrict__ w,
    u16* __restrict__ o, int D, int sx, int so) {
  const float* p = x + (size_t)blockIdx.x * sx;
  u16* q = o + (size_t)blockIdx.x * so;
  float ss = 0.f;
  for (int i = threadIdx.x; i < D; i += 256) { float v = p[i]; ss += v * v; }
#pragma unroll
  for (int off = 32; off; off >>= 1) ss += __shfl_down(ss, off);
  __shared__ float red[4];
  __shared__ float s_inv;
  if ((threadIdx.x & 63) == 0) red[threadIdx.x >> 6] = ss;
  __syncthreads();
  if (threadIdx.x == 0) {
    float t = red[0] + red[1] + red[2] + red[3];
    s_inv = 1.0f / sqrtf(t / (float)D + EPS_);
  }
  __syncthreads();
  float inv = s_inv;
  for (int i = threadIdx.x; i < D; i += 256) q[i] = f2b(w[i] * p[i] * inv);
}

// ---------------------------------------------------------------------------
// RoPE in place on bf16 q_pe. Q: [T][NH*192], pe at +128 per head.
// ---------------------------------------------------------------------------
__global__ void rope_q_bf(u16* __restrict__ Q) {
  int idx = blockIdx.x * blockDim.x + threadIdx.x;   // T*NH*32
  int pair = idx & 31;
  int head = (idx >> 5) & (NH_ - 1);
  int row = idx >> 9;
  if (row >= T_) return;
  int s = row & (S_ - 1);
  float inv = powf(10000.0f, -(float)(2 * pair) * (1.0f / 64.0f));
  float ang = (float)s * inv;
  float c = cosf(ang), sn = sinf(ang);
  u16* p = Q + (size_t)row * (NH_ * DQK) + head * DQK + DN + 2 * pair;
  unsigned u = *(unsigned*)p;
  float e = b2f((u16)(u & 0xffff)), o = b2f((u16)(u >> 16));
  float re = e * c - o * sn;
  float im = e * sn + o * c;
  *(unsigned*)p = (unsigned)f2b(re) | ((unsigned)f2b(im) << 16);
}

// k_pe: fp32 kv_a cols [512,576) (row stride 640), rope -> bf16 KPE [T][64].
__global__ void kpe_bf_kernel(const float* __restrict__ KVa, u16* __restrict__ KPE) {
  int idx = blockIdx.x * blockDim.x + threadIdx.x;   // T*32
  int pair = idx & 31;
  int row = idx >> 5;
  if (row >= T_) return;
  int s = row & (S_ - 1);
  float inv = powf(10000.0f, -(float)(2 * pair) * (1.0f / 64.0f));
  float ang = (float)s * inv;
  float c = cosf(ang), sn = sinf(ang);
  const float* p = KVa + (size_t)row * 640 + KVL + 2 * pair;
  float e = p[0], o = p[1];
  float re = e * c - o * sn;
  float im = e * sn + o * c;
  *(unsigned*)(KPE + (size_t)row * 64 + 2 * pair) =
      (unsigned)f2b(re) | ((unsigned)f2b(im) << 16);
}

// ---------------------------------------------------------------------------
// V transpose: KVbf [T][NH*256] (v at +128 per head) -> Vt [B*NH*128][2048].
// ---------------------------------------------------------------------------
__global__ __launch_bounds__(256) void conv_vt(const u16* __restrict__ KVbf,
                                               u16* __restrict__ Vt) {
  const int h = blockIdx.y, b = blockIdx.z;
  const int s0 = (blockIdx.x >> 1) * 64, d0 = (blockIdx.x & 1) * 64;
  const int t0 = b * S_;
  __shared__ u16 tile[64][72];
  const int tid = threadIdx.x;
#pragma unroll
  for (int i = 0; i < 2; ++i) {
    int c = tid + i * 256;
    int row = c >> 3, off = (c & 7) * 8;
    *(uint4*)&tile[row][off] =
        *(const uint4*)(KVbf + (size_t)(t0 + s0 + row) * 4096 + h * 256 + 128 + d0 + off);
  }
  __syncthreads();
#pragma unroll
  for (int i = 0; i < 2; ++i) {
    int c = tid + i * 256;
    int drow = c >> 3, soff = (c & 7) * 8;
    u16 vals[8];
#pragma unroll
    for (int j = 0; j < 8; ++j) vals[j] = tile[soff + j][drow];
    *(uint4*)(Vt + ((size_t)(b * NH_ + h) * 128 + d0 + drow) * 2048 + s0 + soff) =
        *(uint4*)vals;
  }
}

// ---------------------------------------------------------------------------
// MFMA flash attention (as round 3) — now writes bf16 attn.
// ---------------------------------------------------------------------------
__global__ __launch_bounds__(256) void flash_mfma(
    const u16* __restrict__ Qbf,
    const u16* __restrict__ KVbf,
    const u16* __restrict__ KPE,
    const u16* __restrict__ Vt,
    u16* __restrict__ Out) {
  const int h = blockIdx.y, b = blockIdx.z;
  const int q0 = blockIdx.x * 64;
  const int t0 = b * S_;
  const int tid = threadIdx.x;
  const int wave = tid >> 6, lane = tid & 63, quad = lane >> 4, l16 = lane & 15;

  __shared__ u16 Ks[64][200];
  __shared__ u16 Vs[128][72];
  __shared__ u16 Ps[4][16][72];

  bf16x8 qf[6];
  {
    const u16* qp = Qbf + (size_t)(t0 + q0 + wave * 16 + l16) * (NH_ * DQK) + h * DQK + quad * 8;
#pragma unroll
    for (int c = 0; c < 6; ++c) qf[c] = *(const bf16x8*)(qp + c * 32);
  }

  f32x4 of[8];
#pragma unroll
  for (int i = 0; i < 8; ++i) of[i] = (f32x4){0.f, 0.f, 0.f, 0.f};
  float mrun[4] = {-3e38f, -3e38f, -3e38f, -3e38f};
  float lrun[4] = {0.f, 0.f, 0.f, 0.f};

  for (int kt = 0; kt < S_; kt += 64) {
    __syncthreads();
#pragma unroll
    for (int i = 0; i < 6; ++i) {
      int c = tid + i * 256;
      int row = c / 24, off = c % 24;
      const u16* src = (off < 16)
          ? KVbf + (size_t)(t0 + kt + row) * 4096 + h * 256 + off * 8
          : KPE + (size_t)(t0 + kt + row) * 64 + (off - 16) * 8;
      *(uint4*)&Ks[row][off * 8] = *(const uint4*)src;
    }
#pragma unroll
    for (int i = 0; i < 4; ++i) {
      int c = tid + i * 256;
      int row = c >> 3, off = (c & 7) * 8;
      *(uint4*)&Vs[row][off] =
          *(const uint4*)(Vt + ((size_t)(b * NH_ + h) * 128 + row) * 2048 + kt + off);
    }
    __syncthreads();

    f32x4 sc[4];
#pragma unroll
    for (int kk = 0; kk < 4; ++kk) {
      f32x4 s = (f32x4){0.f, 0.f, 0.f, 0.f};
#pragma unroll
      for (int c = 0; c < 6; ++c) {
        bf16x8 kf = *(const bf16x8*)&Ks[kk * 16 + l16][quad * 8 + c * 32];
        s = __builtin_amdgcn_mfma_f32_16x16x32_bf16(qf[c], kf, s, 0, 0, 0);
      }
      sc[kk] = s;
    }
    float tm[4];
#pragma unroll
    for (int r = 0; r < 4; ++r)
      tm[r] = fmaxf(fmaxf(sc[0][r], sc[1][r]), fmaxf(sc[2][r], sc[3][r]));
#pragma unroll
    for (int off = 1; off < 16; off <<= 1)
#pragma unroll
      for (int r = 0; r < 4; ++r) tm[r] = fmaxf(tm[r], __shfl_xor(tm[r], off, 64));
    float alpha[4], rs[4], p[4][4];
#pragma unroll
    for (int r = 0; r < 4; ++r) {
      float mnew = fmaxf(mrun[r], tm[r]);
      alpha[r] = __expf(mrun[r] - mnew);
      mrun[r] = mnew;
      float s0 = 0.f;
#pragma unroll
      for (int kk = 0; kk < 4; ++kk) {
        float pv = __expf(sc[kk][r] - mnew);
        p[kk][r] = pv;
        s0 += pv;
      }
      rs[r] = s0;
    }
#pragma unroll
    for (int off = 1; off < 16; off <<= 1)
#pragma unroll
      for (int r = 0; r < 4; ++r) rs[r] += __shfl_xor(rs[r], off, 64);
#pragma unroll
    for (int r = 0; r < 4; ++r) lrun[r] = lrun[r] * alpha[r] + rs[r];

#pragma unroll
    for (int kk = 0; kk < 4; ++kk)
#pragma unroll
      for (int r = 0; r < 4; ++r)
        Ps[wave][quad * 4 + r][kk * 16 + l16] = f2b(p[kk][r]);

#pragma unroll
    for (int dt = 0; dt < 8; ++dt)
#pragma unroll
      for (int r = 0; r < 4; ++r) of[dt][r] *= alpha[r];

    bf16x8 pa0 = *(const bf16x8*)&Ps[wave][l16][quad * 8];
    bf16x8 pa1 = *(const bf16x8*)&Ps[wave][l16][32 + quad * 8];
#pragma unroll
    for (int dt = 0; dt < 8; ++dt) {
      bf16x8 v0 = *(const bf16x8*)&Vs[dt * 16 + l16][quad * 8];
      bf16x8 v1 = *(const bf16x8*)&Vs[dt * 16 + l16][32 + quad * 8];
      of[dt] = __builtin_amdgcn_mfma_f32_16x16x32_bf16(pa0, v0, of[dt], 0, 0, 0);
      of[dt] = __builtin_amdgcn_mfma_f32_16x16x32_bf16(pa1, v1, of[dt], 0, 0, 0);
    }
  }

#pragma unroll
  for (int r = 0; r < 4; ++r) {
    float inv = 1.0f / lrun[r];
    u16* op = Out + (size_t)(t0 + q0 + wave * 16 + quad * 4 + r) * (NH_ * DV) + h * DV + l16;
#pragma unroll
    for (int dt = 0; dt < 8; ++dt) op[dt * 16] = f2b(of[dt][r] * inv);
  }
}

// ---------------------------------------------------------------------------
// Workspace layout (float units). One shared weight buffer (disjoint
// lifetimes); q_a region reused for vt+kpe; qn region reused for attn_bf.
// total = 35,389,440 fl = 141.6 MB (< round-2's proven 144 MB).
// ---------------------------------------------------------------------------
extern "C" void kernel_launch(void* const* d_in, const int* in_sizes, int n_in,
                              void* d_out, int out_size, void* d_ws, size_t ws_size,
                              hipStream_t stream) {
  const float* hidden  = (const float*)d_in[0];
  const float* wq_a    = (const float*)d_in[1];
  const float* q_norm  = (const float*)d_in[2];
  const float* wq_b    = (const float*)d_in[3];
  const float* wkv_a   = (const float*)d_in[4];
  const float* kv_norm = (const float*)d_in[5];
  const float* wkv_b   = (const float*)d_in[6];
  const float* wo      = (const float*)d_in[7];
  float* out = (float*)d_out;

  float* ws = (float*)d_ws;
  u16*   hid_bf = (u16*)(ws);                         // 8,388,608 u16  (4,194,304 fl)
  u16*   wbuf   = (u16*)(ws + 4194304);               // <=4,718,592 u16 (2,359,296 fl)
  float* q_a    = ws + 6553600;                       // 6,291,456 fl
  u16*   vt     = (u16*)(ws + 6553600);               // reuse: 8,388,608 u16
  u16*   kpe    = (u16*)(ws + 10747904);              // reuse: 262,144 u16
  float* kv_a   = ws + 12845056;                      // 2,621,440 fl (4096x640)
  u16*   qn_bf  = (u16*)(ws + 15466496);              // 6,291,456 u16
  u16*   attn_bf= (u16*)(ws + 15466496);              // reuse: 8,388,608 u16
  u16*   q_bf   = (u16*)(ws + 19660800);              // 12,582,912 u16
  u16*   kvn_bf = (u16*)(ws + 25952256);              // 2,097,152 u16
  u16*   kv_bf  = (u16*)(ws + 27000832);              // 16,777,216 u16
  const size_t need = (size_t)(27000832 + 8388608) * sizeof(float);
  if (ws_size < need) return;

  // hidden -> bf16
  cvt_bf16<<<8192, 256, 0, stream>>>(hidden, hid_bf, 2097152);

  // ---- q path ----
  cvt_bf16<<<3072, 256, 0, stream>>>(wq_a, wbuf, 786432);
  gemm_mfma<0><<<dim3(QL / 128, T_ / 128), 256, 0, stream>>>(
      hid_bf, H_, wbuf, H_, q_a, nullptr, QL, H_, 1.0f);
  rmsnorm_bf<<<T_, 256, 0, stream>>>(q_a, q_norm, qn_bf, QL, QL, QL);
  cvt_bf16<<<4608, 256, 0, stream>>>(wq_b, wbuf, 1179648);
  gemm_mfma<1><<<dim3(NH_ * DQK / 128, T_ / 128), 256, 0, stream>>>(
      qn_bf, QL, wbuf, QL, nullptr, q_bf, NH_ * DQK, QL, SCALE_);
  rope_q_bf<<<T_ * NH_ * 32 / 256, 256, 0, stream>>>(q_bf);

  // ---- kv path ----
  cvt_wkva<<<1280, 256, 0, stream>>>(wkv_a, wbuf);
  gemm_mfma<0><<<dim3(640 / 128, T_ / 128), 256, 0, stream>>>(
      hid_bf, H_, wbuf, H_, kv_a, nullptr, 640, H_, 1.0f);
  rmsnorm_bf<<<T_, 256, 0, stream>>>(kv_a, kv_norm, kvn_bf, KVL, 640, KVL);
  kpe_bf_kernel<<<T_ * 32 / 256, 256, 0, stream>>>(kv_a, kpe);
  cvt_bf16<<<2048, 256, 0, stream>>>(wkv_b, wbuf, 524288);
  gemm_mfma<1><<<dim3(NH_ * (DN + DV) / 128, T_ / 128), 256, 0, stream>>>(
      kvn_bf, KVL, wbuf, KVL, nullptr, kv_bf, NH_ * (DN + DV), KVL, 1.0f);
  conv_vt<<<dim3(64, NH_, B_), 256, 0, stream>>>(kv_bf, vt);

  // ---- attention ----
  flash_mfma<<<dim3(S_ / 64, NH_, B_), 256, 0, stream>>>(q_bf, kv_bf, kpe, vt, attn_bf);

  // ---- out = attn @ wo.T ----
  cvt_bf16<<<4096, 256, 0, stream>>>(wo, wbuf, 1048576);
  gemm_mfma<0><<<dim3(H_ / 128, T_ / 128), 256, 0, stream>>>(
      attn_bf, NH_ * DV, wbuf, NH_ * DV, out, nullptr, H_, NH_ * DV, 1.0f);
}

// Round 5
// 677.894 us; speedup vs baseline: 6.5656x; 1.0476x over previous
//
#include <hip/hip_runtime.h>
#include <math.h>

#define B_   2
#define S_   2048
#define H_   2048
#define NH_  16
#define T_   (B_*S_)      // 4096 tokens
#define QL   1536
#define KVL  512
#define DN   128
#define DR   64
#define DQK  192          // DN + DR
#define DV   128
#define SCALE_ 0.07216878364870323f   // 1/sqrt(192)
#define EPS_ 1e-6f

typedef unsigned short u16;
typedef __attribute__((ext_vector_type(8))) short bf16x8;  // 8 bf16 = 4 VGPRs
typedef __attribute__((ext_vector_type(4))) float f32x4;   // MFMA C/D frag

__device__ __forceinline__ u16 f2b(float x) {   // fp32 -> bf16 RNE
  union { float f; unsigned u; } v; v.f = x;
  unsigned r = v.u + 0x7FFFu + ((v.u >> 16) & 1u);
  return (u16)(r >> 16);
}
__device__ __forceinline__ float b2f(u16 u) {
  union { unsigned u; float f; } v; v.u = ((unsigned)u) << 16; return v.f;
}

#define GLD16(src, dst) __builtin_amdgcn_global_load_lds(                       \
    (const __attribute__((address_space(1))) unsigned int*)(src),               \
    (__attribute__((address_space(3))) unsigned int*)(dst), 16, 0, 0)

// ---------------------------------------------------------------------------
// fp32 -> bf16 elementwise (n multiple of 4).
// ---------------------------------------------------------------------------
__global__ __launch_bounds__(256) void cvt_bf16(const float* __restrict__ in,
                                                u16* __restrict__ out, int n4) {
  int i = blockIdx.x * 256 + threadIdx.x;
  if (i >= n4) return;
  float4 v = ((const float4*)in)[i];
  u16 r[4] = {f2b(v.x), f2b(v.y), f2b(v.z), f2b(v.w)};
  ((uint2*)out)[i] = *(uint2*)r;
}

// wkv_a (576 x 2048) -> bf16 640 x 2048, rows [576,640) zeroed.
__global__ __launch_bounds__(256) void cvt_wkva(const float* __restrict__ in,
                                                u16* __restrict__ out) {
  int i = blockIdx.x * 256 + threadIdx.x;     // 640*512 float4 chunks
  if (i >= 640 * 512) return;
  int row = i >> 9;
  u16 r[4] = {0, 0, 0, 0};
  if (row < 576) {
    float4 v = ((const float4*)in)[i];
    r[0] = f2b(v.x); r[1] = f2b(v.y); r[2] = f2b(v.z); r[3] = f2b(v.w);
  }
  ((uint2*)out)[i] = *(uint2*)r;
}

// ---------------------------------------------------------------------------
// bf16 MFMA GEMM: C = A @ W^T (as round 4; m97-style granule layout + GLD16).
// ---------------------------------------------------------------------------
template <int OUTMODE>
__global__ __launch_bounds__(256) void gemm_mfma(
    const u16* __restrict__ A, int lda,
    const u16* __restrict__ W, int ldw,
    float* __restrict__ Cf, u16* __restrict__ Cb, int ldc,
    int K, float outscale) {
  __shared__ u16 As[4096];   // 8 KB
  __shared__ u16 Bs[4096];
  const int tid = threadIdx.x;
  const int wave = tid >> 6, lane = tid & 63, quad = lane >> 4, l16 = lane & 15;
  const int wm = (wave >> 1) * 64, wn = (wave & 1) * 64;
  const size_t m0 = (size_t)blockIdx.y * 128, n0 = (size_t)blockIdx.x * 128;

  f32x4 acc[4][4];
#pragma unroll
  for (int i = 0; i < 4; ++i)
#pragma unroll
    for (int j = 0; j < 4; ++j) acc[i][j] = (f32x4){0.f, 0.f, 0.f, 0.f};

  const int g0 = tid, g1 = tid + 256;
  const u16* a0 = A + (m0 + (g0 >> 6) * 16 + (g0 & 15)) * (size_t)lda + ((g0 >> 4) & 3) * 8;
  const u16* a1 = A + (m0 + (g1 >> 6) * 16 + (g1 & 15)) * (size_t)lda + ((g1 >> 4) & 3) * 8;
  const u16* b0 = W + (n0 + (g0 >> 6) * 16 + (g0 & 15)) * (size_t)ldw + ((g0 >> 4) & 3) * 8;
  const u16* b1 = W + (n0 + (g1 >> 6) * 16 + (g1 & 15)) * (size_t)ldw + ((g1 >> 4) & 3) * 8;

  for (int k0 = 0; k0 < K; k0 += 32) {
    __syncthreads();
    GLD16(a0 + k0, &As[g0 * 8]);
    GLD16(a1 + k0, &As[g1 * 8]);
    GLD16(b0 + k0, &Bs[g0 * 8]);
    GLD16(b1 + k0, &Bs[g1 * 8]);
    __syncthreads();

    bf16x8 af[4], bfr[4];
#pragma unroll
    for (int i = 0; i < 4; ++i)
      af[i] = *(const bf16x8*)&As[((wm >> 4) + i) * 512 + quad * 128 + l16 * 8];
#pragma unroll
    for (int j = 0; j < 4; ++j)
      bfr[j] = *(const bf16x8*)&Bs[((wn >> 4) + j) * 512 + quad * 128 + l16 * 8];
#pragma unroll
    for (int i = 0; i < 4; ++i)
#pragma unroll
      for (int j = 0; j < 4; ++j)
        acc[i][j] = __builtin_amdgcn_mfma_f32_16x16x32_bf16(af[i], bfr[j], acc[i][j], 0, 0, 0);
  }

#pragma unroll
  for (int i = 0; i < 4; ++i)
#pragma unroll
    for (int j = 0; j < 4; ++j)
#pragma unroll
      for (int r = 0; r < 4; ++r) {
        size_t m = m0 + wm + i * 16 + quad * 4 + r;
        size_t n = n0 + wn + j * 16 + l16;
        if (OUTMODE == 0) Cf[m * ldc + n] = acc[i][j][r];
        else              Cb[m * ldc + n] = f2b(acc[i][j][r] * outscale);
      }
}

// ---------------------------------------------------------------------------
// RMSNorm: fp32 in (row stride sx), bf16 out (row stride so), D cols.
// ---------------------------------------------------------------------------
__global__ __launch_bounds__(256) void rmsnorm_bf(
    const float* __restrict__ x, const float* __restrict__ w,
    u16* __restrict__ o, int D, int sx, int so) {
  const float* p = x + (size_t)blockIdx.x * sx;
  u16* q = o + (size_t)blockIdx.x * so;
  float ss = 0.f;
  for (int i = threadIdx.x; i < D; i += 256) { float v = p[i]; ss += v * v; }
#pragma unroll
  for (int off = 32; off; off >>= 1) ss += __shfl_down(ss, off);
  __shared__ float red[4];
  __shared__ float s_inv;
  if ((threadIdx.x & 63) == 0) red[threadIdx.x >> 6] = ss;
  __syncthreads();
  if (threadIdx.x == 0) {
    float t = red[0] + red[1] + red[2] + red[3];
    s_inv = 1.0f / sqrtf(t / (float)D + EPS_);
  }
  __syncthreads();
  float inv = s_inv;
  for (int i = threadIdx.x; i < D; i += 256) q[i] = f2b(w[i] * p[i] * inv);
}

// ---------------------------------------------------------------------------
// RoPE in place on bf16 q_pe. Q: [T][NH*192], pe at +128 per head.
// ---------------------------------------------------------------------------
__global__ void rope_q_bf(u16* __restrict__ Q) {
  int idx = blockIdx.x * blockDim.x + threadIdx.x;   // T*NH*32
  int pair = idx & 31;
  int head = (idx >> 5) & (NH_ - 1);
  int row = idx >> 9;
  if (row >= T_) return;
  int s = row & (S_ - 1);
  float inv = powf(10000.0f, -(float)(2 * pair) * (1.0f / 64.0f));
  float ang = (float)s * inv;
  float c = cosf(ang), sn = sinf(ang);
  u16* p = Q + (size_t)row * (NH_ * DQK) + head * DQK + DN + 2 * pair;
  unsigned u = *(unsigned*)p;
  float e = b2f((u16)(u & 0xffff)), o = b2f((u16)(u >> 16));
  float re = e * c - o * sn;
  float im = e * sn + o * c;
  *(unsigned*)p = (unsigned)f2b(re) | ((unsigned)f2b(im) << 16);
}

// k_pe: fp32 kv_a cols [512,576) (row stride 640), rope -> bf16 KPE [T][64].
__global__ void kpe_bf_kernel(const float* __restrict__ KVa, u16* __restrict__ KPE) {
  int idx = blockIdx.x * blockDim.x + threadIdx.x;   // T*32
  int pair = idx & 31;
  int row = idx >> 5;
  if (row >= T_) return;
  int s = row & (S_ - 1);
  float inv = powf(10000.0f, -(float)(2 * pair) * (1.0f / 64.0f));
  float ang = (float)s * inv;
  float c = cosf(ang), sn = sinf(ang);
  const float* p = KVa + (size_t)row * 640 + KVL + 2 * pair;
  float e = p[0], o = p[1];
  float re = e * c - o * sn;
  float im = e * sn + o * c;
  *(unsigned*)(KPE + (size_t)row * 64 + 2 * pair) =
      (unsigned)f2b(re) | ((unsigned)f2b(im) << 16);
}

// ---------------------------------------------------------------------------
// V transpose: KVbf [T][NH*256] (v at +128 per head) -> Vt [B*NH*128][2048].
// ---------------------------------------------------------------------------
__global__ __launch_bounds__(256) void conv_vt(const u16* __restrict__ KVbf,
                                               u16* __restrict__ Vt) {
  const int h = blockIdx.y, b = blockIdx.z;
  const int s0 = (blockIdx.x >> 1) * 64, d0 = (blockIdx.x & 1) * 64;
  const int t0 = b * S_;
  __shared__ u16 tile[64][72];
  const int tid = threadIdx.x;
#pragma unroll
  for (int i = 0; i < 2; ++i) {
    int c = tid + i * 256;
    int row = c >> 3, off = (c & 7) * 8;
    *(uint4*)&tile[row][off] =
        *(const uint4*)(KVbf + (size_t)(t0 + s0 + row) * 4096 + h * 256 + 128 + d0 + off);
  }
  __syncthreads();
#pragma unroll
  for (int i = 0; i < 2; ++i) {
    int c = tid + i * 256;
    int drow = c >> 3, soff = (c & 7) * 8;
    u16 vals[8];
#pragma unroll
    for (int j = 0; j < 8; ++j) vals[j] = tile[soff + j][drow];
    *(uint4*)(Vt + ((size_t)(b * NH_ + h) * 128 + d0 + drow) * 2048 + s0 + soff) =
        *(uint4*)vals;
  }
}

// ---------------------------------------------------------------------------
// MFMA flash attention v2: 128-q-row blocks (32 rows/wave, 2 16-row tiles),
// 64-key tiles, granule LDS layouts (conflict-free b128), GLD16 staging.
// grid (S/128, NH, B), block 256.
// ---------------------------------------------------------------------------
__global__ __launch_bounds__(256, 2) void flash_mfma(
    const u16* __restrict__ Qbf,
    const u16* __restrict__ KVbf,
    const u16* __restrict__ KPE,
    const u16* __restrict__ Vt,
    u16* __restrict__ Out) {
  const int h = blockIdx.y, b = blockIdx.z;
  const int q0 = blockIdx.x * 128;
  const int t0 = b * S_;
  const int tid = threadIdx.x;
  const int wave = tid >> 6, lane = tid & 63, quad = lane >> 4, l16 = lane & 15;
  const int wq = wave * 32;

  // granule layouts (16B granules):
  __shared__ u16 Ks[64 * 192];          // [kk(4)][cc(24)][r16] : key kk*16+r16, kdim cc*8..+8
  __shared__ u16 Vs[128 * 64];          // [dt(8)][kc(8)][r16]  : d dt*16+r16, key kc*8..+8
  __shared__ u16 Ps[4][2][16 * 64];     // per wave,tile: [kc(8)][r16] : q r16, key kc*8..+8

  // Q fragments (2 tiles x 6 k-chunks), held across the whole K loop
  bf16x8 qf[2][6];
#pragma unroll
  for (int t = 0; t < 2; ++t) {
    const u16* qp = Qbf + (size_t)(t0 + q0 + wq + t * 16 + l16) * (NH_ * DQK) + h * DQK + quad * 8;
#pragma unroll
    for (int c = 0; c < 6; ++c) qf[t][c] = *(const bf16x8*)(qp + c * 32);
  }

  // staging source pointers (granule g = i*256+tid)
  const u16* kbase[6]; int kstep[6];
#pragma unroll
  for (int i = 0; i < 6; ++i) {
    int g = i * 256 + tid;
    int r = g & 15, cc = (g >> 4) % 24, kk = (g >> 4) / 24;
    int tok = kk * 16 + r;
    if (cc < 16) { kbase[i] = KVbf + (size_t)(t0 + tok) * 4096 + h * 256 + cc * 8; kstep[i] = 64 * 4096; }
    else         { kbase[i] = KPE + (size_t)(t0 + tok) * 64 + (cc - 16) * 8;       kstep[i] = 64 * 64; }
  }
  const u16* vbase[4];
#pragma unroll
  for (int i = 0; i < 4; ++i) {
    int g = i * 256 + tid;
    int r = g & 15, kc = (g >> 4) & 7, dt = g >> 7;
    vbase[i] = Vt + ((size_t)((b * NH_ + h) * 128) + dt * 16 + r) * 2048 + kc * 8;
  }

  f32x4 of[2][8];
#pragma unroll
  for (int t = 0; t < 2; ++t)
#pragma unroll
    for (int i = 0; i < 8; ++i) of[t][i] = (f32x4){0.f, 0.f, 0.f, 0.f};
  float mrun[2][4], lrun[2][4];
#pragma unroll
  for (int t = 0; t < 2; ++t)
#pragma unroll
    for (int r = 0; r < 4; ++r) { mrun[t][r] = -3e38f; lrun[t][r] = 0.f; }

  for (int kt = 0; kt < S_; kt += 64) {
    __syncthreads();
#pragma unroll
    for (int i = 0; i < 6; ++i) GLD16(kbase[i], &Ks[(i * 256 + tid) * 8]);
#pragma unroll
    for (int i = 0; i < 4; ++i) GLD16(vbase[i] + kt, &Vs[(i * 256 + tid) * 8]);
#pragma unroll
    for (int i = 0; i < 6; ++i) kbase[i] += kstep[i];
    __syncthreads();

    // ---- scores: K-frag shared across both q-tiles ----
    f32x4 sc[2][4];
#pragma unroll
    for (int kk = 0; kk < 4; ++kk) {
      sc[0][kk] = (f32x4){0.f, 0.f, 0.f, 0.f};
      sc[1][kk] = (f32x4){0.f, 0.f, 0.f, 0.f};
#pragma unroll
      for (int c = 0; c < 6; ++c) {
        bf16x8 kf = *(const bf16x8*)&Ks[(kk * 384 + (c * 4 + quad) * 16 + l16) * 8];
        sc[0][kk] = __builtin_amdgcn_mfma_f32_16x16x32_bf16(qf[0][c], kf, sc[0][kk], 0, 0, 0);
        sc[1][kk] = __builtin_amdgcn_mfma_f32_16x16x32_bf16(qf[1][c], kf, sc[1][kk], 0, 0, 0);
      }
    }

    // ---- online softmax per tile ----
    float alpha[2][4];
#pragma unroll
    for (int t = 0; t < 2; ++t) {
      float tm[4], rs[4];
#pragma unroll
      for (int r = 0; r < 4; ++r)
        tm[r] = fmaxf(fmaxf(sc[t][0][r], sc[t][1][r]), fmaxf(sc[t][2][r], sc[t][3][r]));
#pragma unroll
      for (int off = 1; off < 16; off <<= 1)
#pragma unroll
        for (int r = 0; r < 4; ++r) tm[r] = fmaxf(tm[r], __shfl_xor(tm[r], off, 64));
#pragma unroll
      for (int r = 0; r < 4; ++r) {
        float mnew = fmaxf(mrun[t][r], tm[r]);
        alpha[t][r] = __expf(mrun[t][r] - mnew);
        mrun[t][r] = mnew;
        float s0 = 0.f;
#pragma unroll
        for (int kk = 0; kk < 4; ++kk) {
          float pv = __expf(sc[t][kk][r] - mnew);
          sc[t][kk][r] = pv;   // reuse as P
          s0 += pv;
        }
        rs[r] = s0;
      }
#pragma unroll
      for (int off = 1; off < 16; off <<= 1)
#pragma unroll
        for (int r = 0; r < 4; ++r) rs[r] += __shfl_xor(rs[r], off, 64);
#pragma unroll
      for (int r = 0; r < 4; ++r) lrun[t][r] = lrun[t][r] * alpha[t][r] + rs[r];
      // P: C-layout -> granule layout in wave-private LDS
#pragma unroll
      for (int kk = 0; kk < 4; ++kk)
#pragma unroll
        for (int r = 0; r < 4; ++r)
          Ps[wave][t][((kk * 2 + (l16 >> 3)) * 16 + quad * 4 + r) * 8 + (l16 & 7)] =
              f2b(sc[t][kk][r]);
    }

    // ---- O rescale + PV (V-frag shared across both q-tiles) ----
    bf16x8 pa[2][2];
#pragma unroll
    for (int t = 0; t < 2; ++t)
#pragma unroll
      for (int c2 = 0; c2 < 2; ++c2)
        pa[t][c2] = *(const bf16x8*)&Ps[wave][t][((c2 * 4 + quad) * 16 + l16) * 8];
#pragma unroll
    for (int t = 0; t < 2; ++t)
#pragma unroll
      for (int dt = 0; dt < 8; ++dt)
#pragma unroll
        for (int r = 0; r < 4; ++r) of[t][dt][r] *= alpha[t][r];
#pragma unroll
    for (int dt = 0; dt < 8; ++dt) {
#pragma unroll
      for (int c2 = 0; c2 < 2; ++c2) {
        bf16x8 vf = *(const bf16x8*)&Vs[(dt * 128 + (c2 * 4 + quad) * 16 + l16) * 8];
        of[0][dt] = __builtin_amdgcn_mfma_f32_16x16x32_bf16(pa[0][c2], vf, of[0][dt], 0, 0, 0);
        of[1][dt] = __builtin_amdgcn_mfma_f32_16x16x32_bf16(pa[1][c2], vf, of[1][dt], 0, 0, 0);
      }
    }
  }

  // epilogue
#pragma unroll
  for (int t = 0; t < 2; ++t)
#pragma unroll
    for (int r = 0; r < 4; ++r) {
      float inv = 1.0f / lrun[t][r];
      u16* op = Out + (size_t)(t0 + q0 + wq + t * 16 + quad * 4 + r) * (NH_ * DV) + h * DV + l16;
#pragma unroll
      for (int dt = 0; dt < 8; ++dt) op[dt * 16] = f2b(of[t][dt][r] * inv);
    }
}

// ---------------------------------------------------------------------------
// Workspace layout (float units) — identical to round 4.
// ---------------------------------------------------------------------------
extern "C" void kernel_launch(void* const* d_in, const int* in_sizes, int n_in,
                              void* d_out, int out_size, void* d_ws, size_t ws_size,
                              hipStream_t stream) {
  const float* hidden  = (const float*)d_in[0];
  const float* wq_a    = (const float*)d_in[1];
  const float* q_norm  = (const float*)d_in[2];
  const float* wq_b    = (const float*)d_in[3];
  const float* wkv_a   = (const float*)d_in[4];
  const float* kv_norm = (const float*)d_in[5];
  const float* wkv_b   = (const float*)d_in[6];
  const float* wo      = (const float*)d_in[7];
  float* out = (float*)d_out;

  float* ws = (float*)d_ws;
  u16*   hid_bf = (u16*)(ws);                         // 8,388,608 u16
  u16*   wbuf   = (u16*)(ws + 4194304);               // <=4,718,592 u16
  float* q_a    = ws + 6553600;                       // 6,291,456 fl
  u16*   vt     = (u16*)(ws + 6553600);               // reuse: 8,388,608 u16
  u16*   kpe    = (u16*)(ws + 10747904);              // reuse: 262,144 u16
  float* kv_a   = ws + 12845056;                      // 2,621,440 fl (4096x640)
  u16*   qn_bf  = (u16*)(ws + 15466496);              // 6,291,456 u16
  u16*   attn_bf= (u16*)(ws + 15466496);              // reuse: 8,388,608 u16
  u16*   q_bf   = (u16*)(ws + 19660800);              // 12,582,912 u16
  u16*   kvn_bf = (u16*)(ws + 25952256);              // 2,097,152 u16
  u16*   kv_bf  = (u16*)(ws + 27000832);              // 16,777,216 u16
  const size_t need = (size_t)(27000832 + 8388608) * sizeof(float);
  if (ws_size < need) return;

  // hidden -> bf16
  cvt_bf16<<<8192, 256, 0, stream>>>(hidden, hid_bf, 2097152);

  // ---- q path ----
  cvt_bf16<<<3072, 256, 0, stream>>>(wq_a, wbuf, 786432);
  gemm_mfma<0><<<dim3(QL / 128, T_ / 128), 256, 0, stream>>>(
      hid_bf, H_, wbuf, H_, q_a, nullptr, QL, H_, 1.0f);
  rmsnorm_bf<<<T_, 256, 0, stream>>>(q_a, q_norm, qn_bf, QL, QL, QL);
  cvt_bf16<<<4608, 256, 0, stream>>>(wq_b, wbuf, 1179648);
  gemm_mfma<1><<<dim3(NH_ * DQK / 128, T_ / 128), 256, 0, stream>>>(
      qn_bf, QL, wbuf, QL, nullptr, q_bf, NH_ * DQK, QL, SCALE_);
  rope_q_bf<<<T_ * NH_ * 32 / 256, 256, 0, stream>>>(q_bf);

  // ---- kv path ----
  cvt_wkva<<<1280, 256, 0, stream>>>(wkv_a, wbuf);
  gemm_mfma<0><<<dim3(640 / 128, T_ / 128), 256, 0, stream>>>(
      hid_bf, H_, wbuf, H_, kv_a, nullptr, 640, H_, 1.0f);
  rmsnorm_bf<<<T_, 256, 0, stream>>>(kv_a, kv_norm, kvn_bf, KVL, 640, KVL);
  kpe_bf_kernel<<<T_ * 32 / 256, 256, 0, stream>>>(kv_a, kpe);
  cvt_bf16<<<2048, 256, 0, stream>>>(wkv_b, wbuf, 524288);
  gemm_mfma<1><<<dim3(NH_ * (DN + DV) / 128, T_ / 128), 256, 0, stream>>>(
      kvn_bf, KVL, wbuf, KVL, nullptr, kv_bf, NH_ * (DN + DV), KVL, 1.0f);
  conv_vt<<<dim3(64, NH_, B_), 256, 0, stream>>>(kv_bf, vt);

  // ---- attention ----
  flash_mfma<<<dim3(S_ / 128, NH_, B_), 256, 0, stream>>>(q_bf, kv_bf, kpe, vt, attn_bf);

  // ---- out = attn @ wo.T ----
  cvt_bf16<<<4096, 256, 0, stream>>>(wo, wbuf, 1048576);
  gemm_mfma<0><<<dim3(H_ / 128, T_ / 128), 256, 0, stream>>>(
      attn_bf, NH_ * DV, wbuf, NH_ * DV, out, nullptr, H_, NH_ * DV, 1.0f);
}

// Round 7
// 651.622 us; speedup vs baseline: 6.8303x; 1.0403x over previous
//
#include <hip/hip_runtime.h>
#include <math.h>

#define B_   2
#define S_   2048
#define H_   2048
#define NH_  16
#define T_   (B_*S_)      // 4096 tokens
#define QL   1536
#define KVL  512
#define DN   128
#define DR   64
#define DQK  192          // DN + DR
#define DV   128
#define SCALE_ 0.07216878364870323f   // 1/sqrt(192)
#define EPS_ 1e-6f

typedef unsigned short u16;
typedef __attribute__((ext_vector_type(8))) short bf16x8;  // 8 bf16 = 4 VGPRs
typedef __attribute__((ext_vector_type(4))) float f32x4;   // MFMA C/D frag

__device__ __forceinline__ u16 f2b(float x) {   // fp32 -> bf16 RNE
  union { float f; unsigned u; } v; v.f = x;
  unsigned r = v.u + 0x7FFFu + ((v.u >> 16) & 1u);
  return (u16)(r >> 16);
}
__device__ __forceinline__ float b2f(u16 u) {
  union { unsigned u; float f; } v; v.u = ((unsigned)u) << 16; return v.f;
}

#define GLD16(src, dst) __builtin_amdgcn_global_load_lds(                       \
    (const __attribute__((address_space(1))) unsigned int*)(src),               \
    (__attribute__((address_space(3))) unsigned int*)(dst), 16, 0, 0)

__device__ __forceinline__ void cvt4(const float* in, u16* out, int i) {
  float4 v = ((const float4*)in)[i];
  u16 r[4] = {f2b(v.x), f2b(v.y), f2b(v.z), f2b(v.w)};
  ((uint2*)out)[i] = *(uint2*)r;
}

// ---------------------------------------------------------------------------
// One fused conversion kernel: hidden + all 4 weights (wkv_a padded 576->640).
// Segment sizes (float4 units):
//   hidden 2097152 | wq_a 786432 | wq_b 1179648 | wkv_a 327680(out,padded)
//   wkv_b 524288 (4096x512 floats!) | wo 1048576
// total 5,963,776 -> grid 23296 x 256 (exact).
// ---------------------------------------------------------------------------
__global__ __launch_bounds__(256) void cvt_all(
    const float* __restrict__ hid, const float* __restrict__ wqa,
    const float* __restrict__ wqb, const float* __restrict__ wkva,
    const float* __restrict__ wkvb, const float* __restrict__ wo,
    u16* __restrict__ o_hid, u16* __restrict__ o_wqa, u16* __restrict__ o_wqb,
    u16* __restrict__ o_wkva, u16* __restrict__ o_wkvb, u16* __restrict__ o_wo) {
  int i = blockIdx.x * 256 + threadIdx.x;
  if (i < 2097152) { cvt4(hid, o_hid, i); return; }
  i -= 2097152;
  if (i < 786432) { cvt4(wqa, o_wqa, i); return; }
  i -= 786432;
  if (i < 1179648) { cvt4(wqb, o_wqb, i); return; }
  i -= 1179648;
  if (i < 327680) {                       // wkv_a with zero-pad rows [576,640)
    int row = i >> 9;
    u16 r[4] = {0, 0, 0, 0};
    if (row < 576) {
      float4 v = ((const float4*)wkva)[i];
      r[0] = f2b(v.x); r[1] = f2b(v.y); r[2] = f2b(v.z); r[3] = f2b(v.w);
    }
    ((uint2*)o_wkva)[i] = *(uint2*)r;
    return;
  }
  i -= 327680;
  if (i < 524288) { cvt4(wkvb, o_wkvb, i); return; }   // FIXED: was 262144
  i -= 524288;
  if (i < 1048576) cvt4(wo, o_wo, i);
}

// ---------------------------------------------------------------------------
// bf16 MFMA GEMM: C = A @ W^T (m97-style granule layout + GLD16). Unchanged.
// ---------------------------------------------------------------------------
template <int OUTMODE>
__global__ __launch_bounds__(256) void gemm_mfma(
    const u16* __restrict__ A, int lda,
    const u16* __restrict__ W, int ldw,
    float* __restrict__ Cf, u16* __restrict__ Cb, int ldc,
    int K, float outscale) {
  __shared__ u16 As[4096];   // 8 KB
  __shared__ u16 Bs[4096];
  const int tid = threadIdx.x;
  const int wave = tid >> 6, lane = tid & 63, quad = lane >> 4, l16 = lane & 15;
  const int wm = (wave >> 1) * 64, wn = (wave & 1) * 64;
  const size_t m0 = (size_t)blockIdx.y * 128, n0 = (size_t)blockIdx.x * 128;

  f32x4 acc[4][4];
#pragma unroll
  for (int i = 0; i < 4; ++i)
#pragma unroll
    for (int j = 0; j < 4; ++j) acc[i][j] = (f32x4){0.f, 0.f, 0.f, 0.f};

  const int g0 = tid, g1 = tid + 256;
  const u16* a0 = A + (m0 + (g0 >> 6) * 16 + (g0 & 15)) * (size_t)lda + ((g0 >> 4) & 3) * 8;
  const u16* a1 = A + (m0 + (g1 >> 6) * 16 + (g1 & 15)) * (size_t)lda + ((g1 >> 4) & 3) * 8;
  const u16* b0 = W + (n0 + (g0 >> 6) * 16 + (g0 & 15)) * (size_t)ldw + ((g0 >> 4) & 3) * 8;
  const u16* b1 = W + (n0 + (g1 >> 6) * 16 + (g1 & 15)) * (size_t)ldw + ((g1 >> 4) & 3) * 8;

  for (int k0 = 0; k0 < K; k0 += 32) {
    __syncthreads();
    GLD16(a0 + k0, &As[g0 * 8]);
    GLD16(a1 + k0, &As[g1 * 8]);
    GLD16(b0 + k0, &Bs[g0 * 8]);
    GLD16(b1 + k0, &Bs[g1 * 8]);
    __syncthreads();

    bf16x8 af[4], bfr[4];
#pragma unroll
    for (int i = 0; i < 4; ++i)
      af[i] = *(const bf16x8*)&As[((wm >> 4) + i) * 512 + quad * 128 + l16 * 8];
#pragma unroll
    for (int j = 0; j < 4; ++j)
      bfr[j] = *(const bf16x8*)&Bs[((wn >> 4) + j) * 512 + quad * 128 + l16 * 8];
#pragma unroll
    for (int i = 0; i < 4; ++i)
#pragma unroll
      for (int j = 0; j < 4; ++j)
        acc[i][j] = __builtin_amdgcn_mfma_f32_16x16x32_bf16(af[i], bfr[j], acc[i][j], 0, 0, 0);
  }

#pragma unroll
  for (int i = 0; i < 4; ++i)
#pragma unroll
    for (int j = 0; j < 4; ++j)
#pragma unroll
      for (int r = 0; r < 4; ++r) {
        size_t m = m0 + wm + i * 16 + quad * 4 + r;
        size_t n = n0 + wn + j * 16 + l16;
        if (OUTMODE == 0) Cf[m * ldc + n] = acc[i][j][r];
        else              Cb[m * ldc + n] = f2b(acc[i][j][r] * outscale);
      }
}

// ---------------------------------------------------------------------------
// RMSNorm: fp32 in (row stride sx), bf16 out (row stride so), D cols.
// ---------------------------------------------------------------------------
__global__ __launch_bounds__(256) void rmsnorm_bf(
    const float* __restrict__ x, const float* __restrict__ w,
    u16* __restrict__ o, int D, int sx, int so) {
  const float* p = x + (size_t)blockIdx.x * sx;
  u16* q = o + (size_t)blockIdx.x * so;
  float ss = 0.f;
  for (int i = threadIdx.x; i < D; i += 256) { float v = p[i]; ss += v * v; }
#pragma unroll
  for (int off = 32; off; off >>= 1) ss += __shfl_down(ss, off);
  __shared__ float red[4];
  __shared__ float s_inv;
  if ((threadIdx.x & 63) == 0) red[threadIdx.x >> 6] = ss;
  __syncthreads();
  if (threadIdx.x == 0) {
    float t = red[0] + red[1] + red[2] + red[3];
    s_inv = 1.0f / sqrtf(t / (float)D + EPS_);
  }
  __syncthreads();
  float inv = s_inv;
  for (int i = threadIdx.x; i < D; i += 256) q[i] = f2b(w[i] * p[i] * inv);
}

// ---------------------------------------------------------------------------
// RoPE in place on bf16 q_pe. Q: [T][NH*192], pe at +128 per head.
// ---------------------------------------------------------------------------
__global__ void rope_q_bf(u16* __restrict__ Q) {
  int idx = blockIdx.x * blockDim.x + threadIdx.x;   // T*NH*32
  int pair = idx & 31;
  int head = (idx >> 5) & (NH_ - 1);
  int row = idx >> 9;
  if (row >= T_) return;
  int s = row & (S_ - 1);
  float inv = powf(10000.0f, -(float)(2 * pair) * (1.0f / 64.0f));
  float ang = (float)s * inv;
  float c = cosf(ang), sn = sinf(ang);
  u16* p = Q + (size_t)row * (NH_ * DQK) + head * DQK + DN + 2 * pair;
  unsigned u = *(unsigned*)p;
  float e = b2f((u16)(u & 0xffff)), o = b2f((u16)(u >> 16));
  float re = e * c - o * sn;
  float im = e * sn + o * c;
  *(unsigned*)p = (unsigned)f2b(re) | ((unsigned)f2b(im) << 16);
}

// k_pe: fp32 kv_a cols [512,576) (row stride 640), rope -> bf16 KPE [T][64].
__global__ void kpe_bf_kernel(const float* __restrict__ KVa, u16* __restrict__ KPE) {
  int idx = blockIdx.x * blockDim.x + threadIdx.x;   // T*32
  int pair = idx & 31;
  int row = idx >> 5;
  if (row >= T_) return;
  int s = row & (S_ - 1);
  float inv = powf(10000.0f, -(float)(2 * pair) * (1.0f / 64.0f));
  float ang = (float)s * inv;
  float c = cosf(ang), sn = sinf(ang);
  const float* p = KVa + (size_t)row * 640 + KVL + 2 * pair;
  float e = p[0], o = p[1];
  float re = e * c - o * sn;
  float im = e * sn + o * c;
  *(unsigned*)(KPE + (size_t)row * 64 + 2 * pair) =
      (unsigned)f2b(re) | ((unsigned)f2b(im) << 16);
}

// ---------------------------------------------------------------------------
// V transpose: KVbf [T][NH*256] (v at +128 per head) -> Vt [B*NH*128][2048].
// ---------------------------------------------------------------------------
__global__ __launch_bounds__(256) void conv_vt(const u16* __restrict__ KVbf,
                                               u16* __restrict__ Vt) {
  const int h = blockIdx.y, b = blockIdx.z;
  const int s0 = (blockIdx.x >> 1) * 64, d0 = (blockIdx.x & 1) * 64;
  const int t0 = b * S_;
  __shared__ u16 tile[64][72];
  const int tid = threadIdx.x;
#pragma unroll
  for (int i = 0; i < 2; ++i) {
    int c = tid + i * 256;
    int row = c >> 3, off = (c & 7) * 8;
    *(uint4*)&tile[row][off] =
        *(const uint4*)(KVbf + (size_t)(t0 + s0 + row) * 4096 + h * 256 + 128 + d0 + off);
  }
  __syncthreads();
#pragma unroll
  for (int i = 0; i < 2; ++i) {
    int c = tid + i * 256;
    int drow = c >> 3, soff = (c & 7) * 8;
    u16 vals[8];
#pragma unroll
    for (int j = 0; j < 8; ++j) vals[j] = tile[soff + j][drow];
    *(uint4*)(Vt + ((size_t)(b * NH_ + h) * 128 + d0 + drow) * 2048 + s0 + soff) =
        *(uint4*)vals;
  }
}

// ---------------------------------------------------------------------------
// MFMA flash attention v3: 512 threads = 8 waves x 16 q-rows (128-row q-tile),
// 64-key tiles, granule LDS, GLD16 staging. P scratch ALIASES the Ks buffer
// (K dead after score MFMAs; extra barrier). LDS = 24K + 16K = 40960 B ->
// with __launch_bounds__(512,4) (VGPR<=128): 2 blocks/CU = 16 waves/CU.
// grid (S/128, NH, B).
// ---------------------------------------------------------------------------
__global__ __launch_bounds__(512, 4) void flash_mfma(
    const u16* __restrict__ Qbf,
    const u16* __restrict__ KVbf,
    const u16* __restrict__ KPE,
    const u16* __restrict__ Vt,
    u16* __restrict__ Out) {
  const int h = blockIdx.y, b = blockIdx.z;
  const int q0 = blockIdx.x * 128;
  const int t0 = b * S_;
  const int tid = threadIdx.x;
  const int wave = tid >> 6, lane = tid & 63, quad = lane >> 4, l16 = lane & 15;

  __shared__ u16 Ks[64 * 192];   // 24 KB: [kk(4)][cc(24)][r16] granules
  __shared__ u16 Vs[128 * 64];   // 16 KB: [dt(8)][kc(8)][r16] granules
  u16* Ps = &Ks[wave * 1024];    // wave-private 16x64 P (granule layout), aliases Ks

  // Q fragments: wave owns q-rows q0 + wave*16 + [0,16)
  bf16x8 qf[6];
  {
    const u16* qp = Qbf + (size_t)(t0 + q0 + wave * 16 + l16) * (NH_ * DQK) + h * DQK + quad * 8;
#pragma unroll
    for (int c = 0; c < 6; ++c) qf[c] = *(const bf16x8*)(qp + c * 32);
  }

  // staging source pointers (granule g = i*512 + tid)
  const u16* kbase[3]; int kstep[3];
#pragma unroll
  for (int i = 0; i < 3; ++i) {
    int g = i * 512 + tid;
    int r = g & 15, cc = (g >> 4) % 24, kk = (g >> 4) / 24;
    int tok = kk * 16 + r;
    if (cc < 16) { kbase[i] = KVbf + (size_t)(t0 + tok) * 4096 + h * 256 + cc * 8; kstep[i] = 64 * 4096; }
    else         { kbase[i] = KPE + (size_t)(t0 + tok) * 64 + (cc - 16) * 8;       kstep[i] = 64 * 64; }
  }
  const u16* vbase[2];
#pragma unroll
  for (int i = 0; i < 2; ++i) {
    int g = i * 512 + tid;
    int r = g & 15, kc = (g >> 4) & 7, dt = g >> 7;
    vbase[i] = Vt + ((size_t)((b * NH_ + h) * 128) + dt * 16 + r) * 2048 + kc * 8;
  }

  f32x4 of[8];
#pragma unroll
  for (int i = 0; i < 8; ++i) of[i] = (f32x4){0.f, 0.f, 0.f, 0.f};
  float mrun[4] = {-3e38f, -3e38f, -3e38f, -3e38f};
  float lrun[4] = {0.f, 0.f, 0.f, 0.f};

  for (int kt = 0; kt < S_; kt += 64) {
    __syncthreads();                       // prev-iter P/V reads done
#pragma unroll
    for (int i = 0; i < 3; ++i) GLD16(kbase[i], &Ks[(i * 512 + tid) * 8]);
#pragma unroll
    for (int i = 0; i < 2; ++i) GLD16(vbase[i] + kt, &Vs[(i * 512 + tid) * 8]);
#pragma unroll
    for (int i = 0; i < 3; ++i) kbase[i] += kstep[i];
    __syncthreads();                       // staging visible

    // ---- scores: 4 key-subtiles x 6 K-chunks ----
    f32x4 sc[4];
#pragma unroll
    for (int kk = 0; kk < 4; ++kk) {
      f32x4 s = (f32x4){0.f, 0.f, 0.f, 0.f};
#pragma unroll
      for (int c = 0; c < 6; ++c) {
        bf16x8 kf = *(const bf16x8*)&Ks[((kk * 24 + c * 4 + quad) * 16 + l16) * 8];
        s = __builtin_amdgcn_mfma_f32_16x16x32_bf16(qf[c], kf, s, 0, 0, 0);
      }
      sc[kk] = s;
    }

    // ---- online softmax (register-only) ----
    float tm[4], rs[4], alpha[4];
#pragma unroll
    for (int r = 0; r < 4; ++r)
      tm[r] = fmaxf(fmaxf(sc[0][r], sc[1][r]), fmaxf(sc[2][r], sc[3][r]));
#pragma unroll
    for (int off = 1; off < 16; off <<= 1)
#pragma unroll
      for (int r = 0; r < 4; ++r) tm[r] = fmaxf(tm[r], __shfl_xor(tm[r], off, 64));
#pragma unroll
    for (int r = 0; r < 4; ++r) {
      float mnew = fmaxf(mrun[r], tm[r]);
      alpha[r] = __expf(mrun[r] - mnew);
      mrun[r] = mnew;
      float s0 = 0.f;
#pragma unroll
      for (int kk = 0; kk < 4; ++kk) {
        float pv = __expf(sc[kk][r] - mnew);
        sc[kk][r] = pv;        // reuse as P
        s0 += pv;
      }
      rs[r] = s0;
    }
#pragma unroll
    for (int off = 1; off < 16; off <<= 1)
#pragma unroll
      for (int r = 0; r < 4; ++r) rs[r] += __shfl_xor(rs[r], off, 64);
#pragma unroll
    for (int r = 0; r < 4; ++r) lrun[r] = lrun[r] * alpha[r] + rs[r];

    __syncthreads();                       // all waves done reading Ks -> safe to write P

    // P: C-layout -> wave-private granule region (in Ks)
#pragma unroll
    for (int kk = 0; kk < 4; ++kk)
#pragma unroll
      for (int r = 0; r < 4; ++r)
        Ps[((kk * 2 + (l16 >> 3)) * 16 + quad * 4 + r) * 8 + (l16 & 7)] = f2b(sc[kk][r]);

    // O rescale + PV
#pragma unroll
    for (int dt = 0; dt < 8; ++dt)
#pragma unroll
      for (int r = 0; r < 4; ++r) of[dt][r] *= alpha[r];

    bf16x8 pa[2];
#pragma unroll
    for (int c2 = 0; c2 < 2; ++c2)
      pa[c2] = *(const bf16x8*)&Ps[((c2 * 4 + quad) * 16 + l16) * 8];
#pragma unroll
    for (int dt = 0; dt < 8; ++dt) {
#pragma unroll
      for (int c2 = 0; c2 < 2; ++c2) {
        bf16x8 vf = *(const bf16x8*)&Vs[((dt * 8 + c2 * 4 + quad) * 16 + l16) * 8];
        of[dt] = __builtin_amdgcn_mfma_f32_16x16x32_bf16(pa[c2], vf, of[dt], 0, 0, 0);
      }
    }
  }

  // epilogue
#pragma unroll
  for (int r = 0; r < 4; ++r) {
    float inv = 1.0f / lrun[r];
    u16* op = Out + (size_t)(t0 + q0 + wave * 16 + quad * 4 + r) * (NH_ * DV) + h * DV + l16;
#pragma unroll
    for (int dt = 0; dt < 8; ++dt) op[dt * 16] = f2b(of[dt][r] * inv);
  }
}

// ---------------------------------------------------------------------------
// Workspace (float units), total 38,273,024 fl = 153.1 MB.
// Aliases: attn_bf lives in q_a's region (q_a dead after rmsnorm);
//          vt lives in qn_bf+kv_a region (both dead before conv_vt).
// ---------------------------------------------------------------------------
extern "C" void kernel_launch(void* const* d_in, const int* in_sizes, int n_in,
                              void* d_out, int out_size, void* d_ws, size_t ws_size,
                              hipStream_t stream) {
  const float* hidden  = (const float*)d_in[0];
  const float* wq_a    = (const float*)d_in[1];
  const float* q_norm  = (const float*)d_in[2];
  const float* wq_b    = (const float*)d_in[3];
  const float* wkv_a   = (const float*)d_in[4];
  const float* kv_norm = (const float*)d_in[5];
  const float* wkv_b   = (const float*)d_in[6];
  const float* wo      = (const float*)d_in[7];
  float* out = (float*)d_out;

  float* ws = (float*)d_ws;
  u16*   hid_bf  = (u16*)(ws);                  // 8,388,608 u16  -> 4,194,304 fl
  u16*   wqa_bf  = (u16*)(ws + 4194304);        // 3,145,728 u16  -> 1,572,864 fl
  u16*   wqb_bf  = (u16*)(ws + 5767168);        // 4,718,592 u16  -> 2,359,296 fl
  u16*   wkva_bf = (u16*)(ws + 8126464);        // 1,310,720 u16  ->   655,360 fl
  u16*   wkvb_bf = (u16*)(ws + 8781824);        // 2,097,152 u16  -> 1,048,576 fl  (FULL size)
  u16*   wo_bf   = (u16*)(ws + 9830400);        // 4,194,304 u16  -> 2,097,152 fl
  float* q_a     = ws + 11927552;               // 6,291,456 fl (region A)
  u16*   attn_bf = (u16*)(ws + 11927552);       //   alias A: 8,388,608 u16
  u16*   qn_bf   = (u16*)(ws + 18219008);       // 3,145,728 u16 (region B)
  u16*   vt      = (u16*)(ws + 18219008);       //   alias B+C: 8,388,608 u16
  float* kv_a    = ws + 19791872;               // 2,621,440 fl (region C, 4096x640)
  u16*   q_bf    = (u16*)(ws + 22413312);       // 12,582,912 u16
  u16*   kvn_bf  = (u16*)(ws + 28704768);       // 2,097,152 u16
  u16*   kpe     = (u16*)(ws + 29753344);       //   262,144 u16
  u16*   kv_bf   = (u16*)(ws + 29884416);       // 16,777,216 u16
  const size_t need = (size_t)38273024 * sizeof(float);
  if (ws_size < need) return;

  // one fused conversion pass: hidden + all weights
  cvt_all<<<23296, 256, 0, stream>>>(hidden, wq_a, wq_b, wkv_a, wkv_b, wo,
                                     hid_bf, wqa_bf, wqb_bf, wkva_bf, wkvb_bf, wo_bf);

  // ---- q path ----
  gemm_mfma<0><<<dim3(QL / 128, T_ / 128), 256, 0, stream>>>(
      hid_bf, H_, wqa_bf, H_, q_a, nullptr, QL, H_, 1.0f);
  rmsnorm_bf<<<T_, 256, 0, stream>>>(q_a, q_norm, qn_bf, QL, QL, QL);
  gemm_mfma<1><<<dim3(NH_ * DQK / 128, T_ / 128), 256, 0, stream>>>(
      qn_bf, QL, wqb_bf, QL, nullptr, q_bf, NH_ * DQK, QL, SCALE_);
  rope_q_bf<<<T_ * NH_ * 32 / 256, 256, 0, stream>>>(q_bf);

  // ---- kv path ----
  gemm_mfma<0><<<dim3(640 / 128, T_ / 128), 256, 0, stream>>>(
      hid_bf, H_, wkva_bf, H_, kv_a, nullptr, 640, H_, 1.0f);
  rmsnorm_bf<<<T_, 256, 0, stream>>>(kv_a, kv_norm, kvn_bf, KVL, 640, KVL);
  kpe_bf_kernel<<<T_ * 32 / 256, 256, 0, stream>>>(kv_a, kpe);
  gemm_mfma<1><<<dim3(NH_ * (DN + DV) / 128, T_ / 128), 256, 0, stream>>>(
      kvn_bf, KVL, wkvb_bf, KVL, nullptr, kv_bf, NH_ * (DN + DV), KVL, 1.0f);
  conv_vt<<<dim3(64, NH_, B_), 256, 0, stream>>>(kv_bf, vt);

  // ---- attention ----
  flash_mfma<<<dim3(S_ / 128, NH_, B_), 512, 0, stream>>>(q_bf, kv_bf, kpe, vt, attn_bf);

  // ---- out = attn @ wo.T ----
  gemm_mfma<0><<<dim3(H_ / 128, T_ / 128), 256, 0, stream>>>(
      attn_bf, NH_ * DV, wo_bf, NH_ * DV, out, nullptr, H_, NH_ * DV, 1.0f);
}